// Round 13
// baseline (141.164 us; speedup 1.0000x reference)
//
#include <hip/hip_runtime.h>
#include <math.h>

#define NB 4
#define HID 4096
#define CKV 512
#define CQ 1536
#define NH 32
#define HD 128
#define RD 64
#define SS 4096
#define SK 4097
#define SKP 4100  // padded scores row stride

#define SCALE_F 0.07216878364870322f  // 1/sqrt(192)

#define NP1 64   // proj1 k-partials
#define NP2 24   // proj2 k-partials
#define NPV 32   // pv key-chunks (128 keys)
#define NUV 16   // uv c-partials
#define NWO 32   // wo k-partials

#define SC_D4 36    // scores: 144 dims per c-quarter, in float4
#define SC_STR4 37  // scores LDS row stride in float4 (148 floats)

// workspace offsets (floats). ALL regions disjoint (ws is 256 MB).
enum : int {
  WS_QABS  = 0,                        // [NB][NH][CKV] pre-scaled
  WS_QROPE = WS_QABS + NB*NH*CKV,      // [NB][NH][RD]  pre-scaled
  WS_KROPE = WS_QROPE + NB*NH*RD,      // [NB][RD]
  WS_CKV   = WS_KROPE + NB*RD,         // [NB][CKV]
  WS_CQ    = WS_CKV + NB*CKV,          // [NB][CQ] (written by reduce1; unused)
  WS_SCA   = WS_CQ + NB*CQ,            // [NB][NH][SKP] c-quarter 0 -> probs
  WS_SCB   = WS_SCA + NB*NH*SKP,
  WS_SCC   = WS_SCB + NB*NH*SKP,
  WS_SCD   = WS_SCC + NB*NH*SKP,
  WS_P1    = WS_SCD + NB*NH*SKP,       // [NP1][NB][528 f4]
  WS_P2    = WS_P1 + NP1*NB*528*4,     // [NP2][NB][6144]
  WS_OPART = WS_P2 + NP2*NB*6144,      // [NPV][NB][NH][CKV]
  WS_UVPART= WS_OPART + NPV*NB*NH*CKV, // [NUV][NB][HID]
  WS_WOPART= WS_UVPART + NUV*NB*HID,   // [NWO][NB][HID]
  WS_TOTAL = WS_WOPART + NWO*NB*HID
};

__device__ inline void fma4(float4& a, float s, const float4& v) {
  a.x += s*v.x; a.y += s*v.y; a.z += s*v.z; a.w += s*v.w;
}
__device__ inline float dot4(const float4& a, const float4& b) {
  return a.x*b.x + a.y*b.y + a.z*b.z + a.w*b.w;
}

// ------- L1: [bx<576] proj1 -> P1 partials | [else] cache copy --------------
__global__ __launch_bounds__(256)
void k_proj1copy(const float* __restrict__ hidden,
                 const float* __restrict__ Wdkv,
                 const float* __restrict__ Wdq,
                 const float* __restrict__ Wkr,
                 float* __restrict__ ws,
                 const float4* __restrict__ src_ckv,
                 const float4* __restrict__ src_kr,
                 float4* __restrict__ dst_ckv,
                 float4* __restrict__ dst_kr) {
  __shared__ float4 red_s[4][NB][64];
  const int bx = blockIdx.x;
  if (bx < 576) {
    const int gx = bx % 9, gy = bx / 9;
    const int lane = threadIdx.x & 63, ksub = threadIdx.x >> 6;
    const int col4 = gx * 64 + lane;
    const int k0 = gy * 64 + ksub * 16;
    const bool valid = col4 < 528;
    float4 acc[NB] = {};
    if (valid) {
      const float* W; int C4, wcol4;
      if (col4 < 128)      { W = Wdkv; C4 = 128; wcol4 = col4; }
      else if (col4 < 512) { W = Wdq;  C4 = 384; wcol4 = col4 - 128; }
      else                 { W = Wkr;  C4 = 16;  wcol4 = col4 - 512; }
      const float4* wp = (const float4*)W + (size_t)k0 * C4 + wcol4;
      #pragma unroll
      for (int i = 0; i < 16; ++i) {
        float4 w4 = wp[(size_t)i * C4];
        #pragma unroll
        for (int b = 0; b < NB; ++b) fma4(acc[b], hidden[b*HID + k0 + i], w4);
      }
    }
    #pragma unroll
    for (int b = 0; b < NB; ++b) red_s[ksub][b][lane] = acc[b];
    __syncthreads();
    if (ksub == 0 && valid) {
      #pragma unroll
      for (int b = 0; b < NB; ++b) {
        float4 s = red_s[0][b][lane];
        #pragma unroll
        for (int j = 1; j < 4; ++j) {
          float4 v = red_s[j][b][lane];
          s.x += v.x; s.y += v.y; s.z += v.z; s.w += v.w;
        }
        *(float4*)(ws + WS_P1 + ((size_t)(gy*NB + b)*528 + col4)*4) = s;
      }
    }
  } else {
    const int bxc = bx - 576;
    if (bxc < 8192) {
      int b = bxc >> 11;
      int idx = (bxc & 2047) * 256 + threadIdx.x;
      dst_ckv[(size_t)b*(SK*CKV/4) + idx] = src_ckv[(size_t)b*(SS*CKV/4) + idx];
    } else {
      int bx2 = bxc - 8192;
      int b = bx2 >> 8;
      int idx = (bx2 & 255) * 256 + threadIdx.x;
      dst_kr[(size_t)b*(SK*RD/4) + idx] = src_kr[(size_t)b*(SS*RD/4) + idx];
    }
  }
}

// ------- L2: [bx<576] proj2 (self-reduced act from P1) | [else] reduce1 ------
__global__ __launch_bounds__(256)
void k_proj2r1(const float* __restrict__ Wuq,
               const float* __restrict__ Wqr,
               float* __restrict__ ws,
               float* __restrict__ out_ckv,
               float* __restrict__ out_kr) {
  __shared__ float4 red_s[4][NB][64];
  __shared__ float act_s[NB][64];
  const int bx = blockIdx.x;
  const int tid = threadIdx.x;
  if (bx < 576) {
    const int gx = bx % 24, gy = bx / 24;
    {
      const int b = tid >> 6, i = tid & 63;
      const int k = gy * 64 + i;
      const float* base = ws + WS_P1 + (size_t)b*2112 + 512 + k;
      float s = 0.f;
      #pragma unroll 8
      for (int p = 0; p < NP1; ++p) s += base[(size_t)p*NB*2112];
      act_s[b][i] = s;
    }
    __syncthreads();
    const int lane = tid & 63, ksub = tid >> 6;
    const int col4 = gx * 64 + lane;
    const float* W; int C4, wcol4;
    if (col4 < 1024) { W = Wuq; C4 = 1024; wcol4 = col4; }
    else             { W = Wqr; C4 = 512;  wcol4 = col4 - 1024; }
    const float4* wp = (const float4*)W + (size_t)(gy*64 + ksub*16) * C4 + wcol4;
    float4 acc[NB] = {};
    #pragma unroll
    for (int i = 0; i < 16; ++i) {
      float4 w4 = wp[(size_t)i * C4];
      #pragma unroll
      for (int b = 0; b < NB; ++b) fma4(acc[b], act_s[b][ksub*16 + i], w4);
    }
    #pragma unroll
    for (int b = 0; b < NB; ++b) red_s[ksub][b][lane] = acc[b];
    __syncthreads();
    if (ksub == 0) {
      #pragma unroll
      for (int b = 0; b < NB; ++b) {
        float4 s = red_s[0][b][lane];
        #pragma unroll
        for (int j = 1; j < 4; ++j) {
          float4 v = red_s[j][b][lane];
          s.x += v.x; s.y += v.y; s.z += v.z; s.w += v.w;
        }
        *(float4*)(ws + WS_P2 + (size_t)(gy*NB + b)*6144 + col4*4) = s;
      }
    }
  } else {
    const int w = (bx - 576) * 256 + tid;
    if (w >= 528*NB) return;
    const int b = w / 528, col4 = w % 528;
    float4 s = {};
    #pragma unroll 8
    for (int p = 0; p < NP1; ++p) {
      float4 v = *(const float4*)(ws + WS_P1 + ((size_t)(p*NB + b)*528 + col4)*4);
      s.x += v.x; s.y += v.y; s.z += v.z; s.w += v.w;
    }
    if (col4 < 128) {
      *(float4*)(ws + WS_CKV + b*CKV + col4*4) = s;
      *(float4*)(out_ckv + (size_t)b*SK*CKV + (size_t)SS*CKV + col4*4) = s;
    } else if (col4 < 512) {
      *(float4*)(ws + WS_CQ + b*CQ + (col4 - 128)*4) = s;
    } else {
      const int c0 = (col4 - 512) * 4;
      const double LN1E4 = 9.210340371976184;
      int i0 = c0 >> 1;
      double a0 = 4096.0 * exp(-(double)i0 / 32.0 * LN1E4);
      double a1 = 4096.0 * exp(-(double)(i0 + 1) / 32.0 * LN1E4);
      float c0f = (float)cos(a0), s0f = (float)sin(a0);
      float c1f = (float)cos(a1), s1f = (float)sin(a1);
      float4 o;
      o.x = s.x*c0f - s.y*s0f;  o.y = s.x*s0f + s.y*c0f;
      o.z = s.z*c1f - s.w*s1f;  o.w = s.z*s1f + s.w*c1f;
      *(float4*)(ws + WS_KROPE + b*RD + c0) = o;
      *(float4*)(out_kr + (size_t)b*SK*RD + (size_t)SS*RD + c0) = o;
    }
  }
}

// -------- L3: q_abs = q_C @ W_UK^T (×SCALE), P2-reduce fused; q_R RoPE -------
__global__ __launch_bounds__(256)
void k_absorb_rope(const float* __restrict__ Wuk,
                   float* __restrict__ ws) {
  const int bid = blockIdx.x, tid = threadIdx.x;
  if (bid < 256) {
    const int h = bid >> 3, cq = bid & 7;
    __shared__ float qc_s[NB][HD];
    __shared__ float part_s[NB][256];
    for (int e = tid; e < NB*HD; e += 256) {
      int b = e >> 7, d = e & 127;
      float v = 0.f;
      #pragma unroll
      for (int p = 0; p < NP2; ++p)
        v += ws[WS_P2 + (size_t)(p*NB + b)*6144 + h*HD + d];
      qc_s[b][d] = v;
    }
    __syncthreads();
    const int c = cq*64 + (tid & 63);
    const int dg = tid >> 6;
    const float4* wrow = (const float4*)(Wuk + (size_t)c*(NH*HD) + h*HD + dg*32);
    float acc[NB] = {0,0,0,0};
    #pragma unroll
    for (int d4 = 0; d4 < 8; ++d4) {
      float4 w4 = wrow[d4];
      #pragma unroll
      for (int b = 0; b < NB; ++b)
        acc[b] += dot4(w4, *(const float4*)&qc_s[b][dg*32 + d4*4]);
    }
    #pragma unroll
    for (int b = 0; b < NB; ++b) part_s[b][tid] = acc[b];
    __syncthreads();
    if (tid < 64) {
      #pragma unroll
      for (int b = 0; b < NB; ++b) {
        float v = part_s[b][tid] + part_s[b][tid+64] + part_s[b][tid+128] + part_s[b][tid+192];
        ws[WS_QABS + (size_t)(b*NH + h)*CKV + cq*64 + tid] = v * SCALE_F;
      }
    }
  } else {
    const int b = bid - 256;
    const double LN1E4 = 9.210340371976184;
    for (int pid = tid; pid < NH*32; pid += 256) {
      int h = pid >> 5, i = pid & 31;
      float x1 = 0.f, x2 = 0.f;
      #pragma unroll
      for (int p = 0; p < NP2; ++p) {
        const float* base = ws + WS_P2 + (size_t)(p*NB + b)*6144 + 4096 + h*RD + 2*i;
        x1 += base[0]; x2 += base[1];
      }
      double ang = 4096.0 * exp(-(double)i / 32.0 * LN1E4);
      float cs = (float)cos(ang), sn = (float)sin(ang);
      ws[WS_QROPE + (b*NH + h)*RD + 2*i]     = (x1*cs - x2*sn) * SCALE_F;
      ws[WS_QROPE + (b*NH + h)*RD + 2*i + 1] = (x1*sn + x2*cs) * SCALE_F;
    }
  }
}

// ---------------- L4: scores v7 — 4h×2k register tile, broadcast q ----------
// block: 32 heads × 64 keys × 144-dim c-quarter; grid (65, 4, 4) = 1040.
// LDS 56.8 KB (kv 64 rows + q 32 rows) -> 2 blocks/CU. Thread = heads
// hg*4..+3 (broadcast within 32-lane group) × keys kg, kg+32.
// 6 LDS b128 per 32 FMA (was 5 per 16).
__global__ __launch_bounds__(256)
void k_scores(const float* __restrict__ kv_cache,
              const float* __restrict__ kr_cache,
              float* __restrict__ ws) {
  __shared__ float4 kv_s[64 * SC_STR4];
  __shared__ float4 q_s[32 * SC_STR4];
  const int tid = threadIdx.x;
  const int b  = blockIdx.z;
  const int cs = blockIdx.y;
  const int k0 = blockIdx.x * 64;
  // ---- stage kv: 64 rows, 4 threads/row, 9 f4 each
  {
    const int row = tid >> 2, c4a = (tid & 3) * 9;
    const int k = k0 + row;
    const float4* kvr = nullptr; const float4* krr = nullptr;
    if (k < SS)       { kvr = (const float4*)(kv_cache + ((size_t)b*SS + k)*CKV);
                        krr = (const float4*)(kr_cache + ((size_t)b*SS + k)*RD); }
    else if (k == SS) { kvr = (const float4*)(ws + WS_CKV + b*CKV);
                        krr = (const float4*)(ws + WS_KROPE + b*RD); }
    #pragma unroll
    for (int i = 0; i < 9; ++i) {
      int c4 = c4a + i;                 // < 36
      int g4 = cs * SC_D4 + c4;
      float4 v = make_float4(0.f, 0.f, 0.f, 0.f);
      if (kvr) v = (g4 < 128) ? kvr[g4] : krr[g4 - 128];
      kv_s[row * SC_STR4 + c4] = v;
    }
    // ---- stage q: 32 rows, 8 threads/row, 5 guarded f4
    const int r = tid >> 3, t7 = tid & 7;
    const float4* qa = (const float4*)(ws + WS_QABS + (size_t)(b*NH + r)*CKV);
    const float4* qr = (const float4*)(ws + WS_QROPE + (size_t)(b*NH + r)*RD);
    #pragma unroll
    for (int i = 0; i < 5; ++i) {
      int c4 = t7 + 8*i;
      if (c4 < SC_D4) {
        int g4 = cs * SC_D4 + c4;
        q_s[r * SC_STR4 + c4] = (g4 < 128) ? qa[g4] : qr[g4 - 128];
      }
    }
  }
  __syncthreads();
  const int hg = tid >> 5;        // 0..7 -> heads hg*4..+3 (uniform per 32 lanes)
  const int kg = tid & 31;        // keys kg, kg+32
  const float4* q0 = &q_s[(hg*4 + 0) * SC_STR4];
  const float4* q1 = &q_s[(hg*4 + 1) * SC_STR4];
  const float4* q2 = &q_s[(hg*4 + 2) * SC_STR4];
  const float4* q3 = &q_s[(hg*4 + 3) * SC_STR4];
  const float4* kva = &kv_s[kg * SC_STR4];
  const float4* kvb = &kv_s[(kg + 32) * SC_STR4];
  float acc[4][2] = {};
  #pragma unroll 6
  for (int c4 = 0; c4 < SC_D4; ++c4) {
    float4 ka4 = kva[c4], kb4 = kvb[c4];
    float4 a0 = q0[c4], a1 = q1[c4], a2 = q2[c4], a3 = q3[c4];
    acc[0][0] += dot4(a0, ka4);  acc[0][1] += dot4(a0, kb4);
    acc[1][0] += dot4(a1, ka4);  acc[1][1] += dot4(a1, kb4);
    acc[2][0] += dot4(a2, ka4);  acc[2][1] += dot4(a2, kb4);
    acc[3][0] += dot4(a3, ka4);  acc[3][1] += dot4(a3, kb4);
  }
  float* sbuf = ws + (cs == 0 ? WS_SCA : cs == 1 ? WS_SCB : cs == 2 ? WS_SCC : WS_SCD);
  const int ka = k0 + kg, kb = k0 + kg + 32;
  #pragma unroll
  for (int i = 0; i < 4; ++i) {
    float* srow = sbuf + (size_t)(b*NH + hg*4 + i)*SKP;
    if (ka < SK) srow[ka] = acc[i][0];
    if (kb < SK) srow[kb] = acc[i][1];
  }
}

// ---------------- L5: softmax(SCA+SCB+SCC+SCD+mask) -> probs in SCA ---------
__global__ __launch_bounds__(256)
void k_softmax(const float* __restrict__ mask, float* __restrict__ ws) {
  __shared__ float red[256];
  const int tid = threadIdx.x;
  const int b = blockIdx.x >> 5;
  float* sa = ws + WS_SCA + (size_t)blockIdx.x * SKP;
  const float* sb = ws + WS_SCB + (size_t)blockIdx.x * SKP;
  const float* sc = ws + WS_SCC + (size_t)blockIdx.x * SKP;
  const float* sd = ws + WS_SCD + (size_t)blockIdx.x * SKP;
  const float* mrow = mask + (size_t)b * SK;
  float v[17];
  float m = -INFINITY;
  #pragma unroll
  for (int r = 0; r < 17; ++r) {
    int k = tid + r*256;
    v[r] = (k < SK) ? (sa[k] + sb[k] + sc[k] + sd[k] + mrow[k] * (-1e9f)) : -INFINITY;
    m = fmaxf(m, v[r]);
  }
  red[tid] = m; __syncthreads();
  for (int st = 128; st > 0; st >>= 1) {
    if (tid < st) red[tid] = fmaxf(red[tid], red[tid+st]);
    __syncthreads();
  }
  m = red[0]; __syncthreads();
  float e[17];
  float l = 0.f;
  #pragma unroll
  for (int r = 0; r < 17; ++r) {
    int k = tid + r*256;
    e[r] = (k < SK) ? __expf(v[r] - m) : 0.f;
    l += e[r];
  }
  red[tid] = l; __syncthreads();
  for (int st = 128; st > 0; st >>= 1) {
    if (tid < st) red[tid] += red[tid+st];
    __syncthreads();
  }
  float inv = 1.f / red[0];
  #pragma unroll
  for (int r = 0; r < 17; ++r) {
    int k = tid + r*256;
    if (k < SK) sa[k] = e[r] * inv;
  }
}

// ---------------- L6: o_latent partials — LDS-staged probs ------------------
__global__ __launch_bounds__(256)
void k_pv(const float* __restrict__ kv_cache, float* __restrict__ ws) {
  __shared__ float p_s[32][132];
  const int tid = threadIdx.x;
  const int c4 = tid & 15, hg = tid >> 4;
  const int b  = blockIdx.z;
  const int c  = blockIdx.y * 64 + c4 * 4;
  const int k0 = blockIdx.x * 128;
  #pragma unroll
  for (int j = 0; j < 4; ++j) {
    int e = tid + j*256;
    int h = e >> 5, k4 = e & 31;
    *(float4*)&p_s[h][k4*4] =
        *(const float4*)(ws + WS_SCA + (size_t)(b*NH + h)*SKP + k0 + k4*4);
  }
  __syncthreads();
  const float* kvp = kv_cache + ((size_t)b*SS + k0)*CKV + c;
  float4 acc0 = {}, acc1 = {};
  #pragma unroll 4
  for (int kk = 0; kk < 128; kk += 4) {
    float4 kv4[4];
    #pragma unroll
    for (int j = 0; j < 4; ++j)
      kv4[j] = *(const float4*)(kvp + (size_t)(kk + j)*CKV);
    float4 p4a = *(const float4*)&p_s[hg][kk];
    float4 p4b = *(const float4*)&p_s[hg + 16][kk];
    fma4(acc0, p4a.x, kv4[0]); fma4(acc1, p4b.x, kv4[0]);
    fma4(acc0, p4a.y, kv4[1]); fma4(acc1, p4b.y, kv4[1]);
    fma4(acc0, p4a.z, kv4[2]); fma4(acc1, p4b.z, kv4[2]);
    fma4(acc0, p4a.w, kv4[3]); fma4(acc1, p4b.w, kv4[3]);
  }
  if (blockIdx.x == NPV - 1) {
    float4 kv = *(const float4*)(ws + WS_CKV + b*CKV + c);
    float pa = ws[WS_SCA + (size_t)(b*NH + hg)*SKP + SS];
    float pb = ws[WS_SCA + (size_t)(b*NH + hg + 16)*SKP + SS];
    fma4(acc0, pa, kv);
    fma4(acc1, pb, kv);
  }
  *(float4*)(ws + WS_OPART + (((size_t)blockIdx.x*NB + b)*NH + hg)*CKV + c) = acc0;
  *(float4*)(ws + WS_OPART + (((size_t)blockIdx.x*NB + b)*NH + hg + 16)*CKV + c) = acc1;
}

// ------- L7: uv with OPART self-reduce pre-phase -----------------------------
__global__ __launch_bounds__(256)
void k_uv2(const float* __restrict__ Wuv, float* __restrict__ ws) {
  __shared__ float4 red_s[4][NB][64];
  __shared__ float ol_s[NB][2][32];
  const int tid = threadIdx.x;
  const int x = blockIdx.x & 15, y = blockIdx.x >> 4;
  {
    const int b = tid >> 6, hh = (tid >> 5) & 1, ci = tid & 31;
    const float* base = ws + WS_OPART + ((size_t)b*NH + (2*x + hh))*CKV + y*32 + ci;
    float s = 0.f;
    #pragma unroll 8
    for (int p = 0; p < NPV; ++p) s += base[(size_t)p*(NB*NH*CKV)];
    ol_s[b][hh][ci] = s;
  }
  __syncthreads();
  const int lane = tid & 63, csub = tid >> 6;
  const int col4 = x * 64 + lane;
  const int hh = (col4 >> 5) & 1;
  const float4* wp = (const float4*)Wuv + (size_t)(y*32 + csub*8) * 1024 + col4;
  float4 acc[NB] = {};
  #pragma unroll
  for (int i = 0; i < 8; ++i) {
    float4 w4 = wp[(size_t)i * 1024];
    #pragma unroll
    for (int b = 0; b < NB; ++b)
      fma4(acc[b], ol_s[b][hh][csub*8 + i], w4);
  }
  #pragma unroll
  for (int b = 0; b < NB; ++b) red_s[csub][b][lane] = acc[b];
  __syncthreads();
  if (csub == 0) {
    #pragma unroll
    for (int b = 0; b < NB; ++b) {
      float4 s = red_s[0][b][lane];
      #pragma unroll
      for (int j = 1; j < 4; ++j) {
        float4 v = red_s[j][b][lane];
        s.x += v.x; s.y += v.y; s.z += v.z; s.w += v.w;
      }
      *(float4*)(ws + WS_UVPART + (size_t)(y*NB + b)*HID + col4*4) = s;
    }
  }
}

// ------- L8: wo with UVPART self-reduce pre-phase ----------------------------
__global__ __launch_bounds__(256)
void k_wo2(const float* __restrict__ Wo, float* __restrict__ ws) {
  __shared__ float4 red_s[4][NB][64];
  __shared__ float at_s[NB][128];
  const int tid = threadIdx.x;
  const int x = blockIdx.x & 15, y = blockIdx.x >> 4;
  {
    const int b = tid >> 6, q = tid & 63;
    #pragma unroll
    for (int e = 0; e < 2; ++e) {
      int idx = q*2 + e;
      const float* base = ws + WS_UVPART + (size_t)b*HID + y*128 + idx;
      float s = 0.f;
      #pragma unroll
      for (int p = 0; p < NUV; ++p) s += base[(size_t)p*(NB*HID)];
      at_s[b][idx] = s;
    }
  }
  __syncthreads();
  const int lane = tid & 63, ksub = tid >> 6;
  const int col4 = x * 64 + lane;
  const float4* wp = (const float4*)Wo + (size_t)(y*128 + ksub*32) * 1024 + col4;
  float4 acc[NB] = {};
  #pragma unroll 8
  for (int i = 0; i < 32; ++i) {
    float4 w4 = wp[(size_t)i * 1024];
    #pragma unroll
    for (int b = 0; b < NB; ++b)
      fma4(acc[b], at_s[b][ksub*32 + i], w4);
  }
  #pragma unroll
  for (int b = 0; b < NB; ++b) red_s[ksub][b][lane] = acc[b];
  __syncthreads();
  if (ksub == 0) {
    #pragma unroll
    for (int b = 0; b < NB; ++b) {
      float4 s = red_s[0][b][lane];
      #pragma unroll
      for (int j = 1; j < 4; ++j) {
        float4 v = red_s[j][b][lane];
        s.x += v.x; s.y += v.y; s.z += v.z; s.w += v.w;
      }
      *(float4*)(ws + WS_WOPART + (size_t)(y*NB + b)*HID + col4*4) = s;
    }
  }
}

// ---------------- L9: out = sum_p WOPART[p] ----------------------------------
__global__ __launch_bounds__(256)
void k_reduce5(const float* __restrict__ ws, float* __restrict__ out) {
  const int idx = blockIdx.x * 256 + threadIdx.x;
  float4 s = {};
  #pragma unroll 8
  for (int p = 0; p < NWO; ++p) {
    float4 v = *(const float4*)(ws + WS_WOPART + (size_t)p*(NB*HID) + (size_t)idx*4);
    s.x += v.x; s.y += v.y; s.z += v.z; s.w += v.w;
  }
  *(float4*)(out + (size_t)idx*4) = s;
}

extern "C" void kernel_launch(void* const* d_in, const int* in_sizes, int n_in,
                              void* d_out, int out_size, void* d_ws, size_t ws_size,
                              hipStream_t stream) {
  (void)in_sizes; (void)n_in; (void)out_size; (void)ws_size;
  const float* hidden = (const float*)d_in[0];
  const float* mask   = (const float*)d_in[1];
  const float* ckv_c  = (const float*)d_in[2];
  const float* kr_c   = (const float*)d_in[3];
  const float* Wdkv   = (const float*)d_in[4];
  const float* Wuk    = (const float*)d_in[5];
  const float* Wuv    = (const float*)d_in[6];
  const float* Wdq    = (const float*)d_in[7];
  const float* Wuq    = (const float*)d_in[8];
  const float* Wqr    = (const float*)d_in[9];
  const float* Wkr    = (const float*)d_in[10];
  const float* Wo     = (const float*)d_in[11];
  float* out = (float*)d_out;
  float* ws  = (float*)d_ws;
  float* out_ckv = out + NB*HID;
  float* out_kr  = out + NB*HID + (size_t)NB*SK*CKV;

  k_proj1copy<<<9792, 256, 0, stream>>>(hidden, Wdkv, Wdq, Wkr, ws,
                                        (const float4*)ckv_c, (const float4*)kr_c,
                                        (float4*)out_ckv, (float4*)out_kr);
  k_proj2r1<<<585, 256, 0, stream>>>(Wuq, Wqr, ws, out_ckv, out_kr);
  k_absorb_rope<<<260, 256, 0, stream>>>(Wuk, ws);
  k_scores<<<dim3(65, 4, 4), 256, 0, stream>>>(ckv_c, kr_c, ws);
  k_softmax<<<NB*NH, 256, 0, stream>>>(mask, ws);
  k_pv<<<dim3(NPV, 8, 4), 256, 0, stream>>>(ckv_c, ws);
  k_uv2<<<256, 256, 0, stream>>>(Wuv, ws);
  k_wo2<<<512, 256, 0, stream>>>(Wo, ws);
  k_reduce5<<<16, 256, 0, stream>>>(ws, out);
}

// Round 14
// 112.635 us; speedup vs baseline: 1.2533x; 1.2533x over previous
//
#include <hip/hip_runtime.h>
#include <math.h>

#define NB 4
#define HID 4096
#define CKV 512
#define CQ 1536
#define NH 32
#define HD 128
#define RD 64
#define SS 4096
#define SK 4097
#define SKP 4100  // padded scores row stride

#define SCALE_F 0.07216878364870322f  // 1/sqrt(192)

#define NP1 64   // proj1 k-partials
#define NP2 24   // proj2 k-partials
#define NPV 32   // pv key-chunks (128 keys)
#define NUV 16   // uv c-partials
#define NWO 32   // wo k-partials

#define KD   576      // latent 512 + rope 64, contiguous bf16 rows
#define QKB_STR 584   // LDS bf16 row stride (16B-aligned, +8 pad)

typedef __attribute__((ext_vector_type(8))) short short8v;
typedef __attribute__((ext_vector_type(4))) float f32x4;

// workspace offsets (floats). ALL regions disjoint (ws is 256 MB).
enum : int {
  WS_QABS  = 0,                        // [NB][NH][CKV] f32, pre-scaled
  WS_QROPE = WS_QABS + NB*NH*CKV,      // [NB][NH][RD]  f32, pre-scaled
  WS_KROPE = WS_QROPE + NB*NH*RD,      // [NB][RD]
  WS_CKV   = WS_KROPE + NB*RD,         // [NB][CKV]
  WS_CQ    = WS_CKV + NB*CKV,          // [NB][CQ]
  WS_SCA   = WS_CQ + NB*CQ,            // [NB][NH][SKP] scores -> probs
  WS_P1    = WS_SCA + NB*NH*SKP,       // [NP1][NB][528 f4]
  WS_P2    = WS_P1 + NP1*NB*528*4,     // [NP2][NB][6144]
  WS_OPART = WS_P2 + NP2*NB*6144,      // [NPV][NB][NH][CKV]
  WS_UVPART= WS_OPART + NPV*NB*NH*CKV, // [NUV][NB][HID]
  WS_WOPART= WS_UVPART + NUV*NB*HID,   // [NWO][NB][HID]
  WS_KVBF  = WS_WOPART + NWO*NB*HID,   // bf16 [NB][SK][576] (as floats /2)
  WS_QBF   = WS_KVBF + (NB*SK*KD)/2,   // bf16 [NB][NH][576]
  WS_TOTAL = WS_QBF + (NB*NH*KD)/2
};

__device__ inline void fma4(float4& a, float s, const float4& v) {
  a.x += s*v.x; a.y += s*v.y; a.z += s*v.z; a.w += s*v.w;
}
__device__ inline float dot4(const float4& a, const float4& b) {
  return a.x*b.x + a.y*b.y + a.z*b.z + a.w*b.w;
}
__device__ inline unsigned short f2bf(float f) {
  union { float f; unsigned int u; } v; v.f = f;
  unsigned int r = v.u + 0x7FFFu + ((v.u >> 16) & 1u);
  return (unsigned short)(r >> 16);
}
__device__ inline ushort4 f2bf4(float4 v) {
  ushort4 r; r.x = f2bf(v.x); r.y = f2bf(v.y); r.z = f2bf(v.z); r.w = f2bf(v.w);
  return r;
}

// ------- L1: [bx<576] proj1 -> P1 partials | [else] cache copy + bf16 copy --
__global__ __launch_bounds__(256)
void k_proj1copy(const float* __restrict__ hidden,
                 const float* __restrict__ Wdkv,
                 const float* __restrict__ Wdq,
                 const float* __restrict__ Wkr,
                 float* __restrict__ ws,
                 const float4* __restrict__ src_ckv,
                 const float4* __restrict__ src_kr,
                 float4* __restrict__ dst_ckv,
                 float4* __restrict__ dst_kr) {
  __shared__ float4 red_s[4][NB][64];
  unsigned short* kvbf = (unsigned short*)(ws + WS_KVBF);
  const int bx = blockIdx.x;
  if (bx < 576) {
    const int gx = bx % 9, gy = bx / 9;
    const int lane = threadIdx.x & 63, ksub = threadIdx.x >> 6;
    const int col4 = gx * 64 + lane;
    const int k0 = gy * 64 + ksub * 16;
    const bool valid = col4 < 528;
    float4 acc[NB] = {};
    if (valid) {
      const float* W; int C4, wcol4;
      if (col4 < 128)      { W = Wdkv; C4 = 128; wcol4 = col4; }
      else if (col4 < 512) { W = Wdq;  C4 = 384; wcol4 = col4 - 128; }
      else                 { W = Wkr;  C4 = 16;  wcol4 = col4 - 512; }
      const float4* wp = (const float4*)W + (size_t)k0 * C4 + wcol4;
      #pragma unroll
      for (int i = 0; i < 16; ++i) {
        float4 w4 = wp[(size_t)i * C4];
        #pragma unroll
        for (int b = 0; b < NB; ++b) fma4(acc[b], hidden[b*HID + k0 + i], w4);
      }
    }
    #pragma unroll
    for (int b = 0; b < NB; ++b) red_s[ksub][b][lane] = acc[b];
    __syncthreads();
    if (ksub == 0 && valid) {
      #pragma unroll
      for (int b = 0; b < NB; ++b) {
        float4 s = red_s[0][b][lane];
        #pragma unroll
        for (int j = 1; j < 4; ++j) {
          float4 v = red_s[j][b][lane];
          s.x += v.x; s.y += v.y; s.z += v.z; s.w += v.w;
        }
        *(float4*)(ws + WS_P1 + ((size_t)(gy*NB + b)*528 + col4)*4) = s;
      }
    }
  } else {
    const int bxc = bx - 576;
    if (bxc < 8192) {
      int b = bxc >> 11;
      int idx = (bxc & 2047) * 256 + threadIdx.x;
      float4 v = src_ckv[(size_t)b*(SS*CKV/4) + idx];
      dst_ckv[(size_t)b*(SK*CKV/4) + idx] = v;
      int off = idx * 4;
      int k = off >> 9, c = off & 511;
      *(ushort4*)(kvbf + ((size_t)b*SK + k)*KD + c) = f2bf4(v);
    } else {
      int bx2 = bxc - 8192;
      int b = bx2 >> 8;
      int idx = (bx2 & 255) * 256 + threadIdx.x;
      float4 v = src_kr[(size_t)b*(SS*RD/4) + idx];
      dst_kr[(size_t)b*(SK*RD/4) + idx] = v;
      int off = idx * 4;
      int k = off >> 6, rr = off & 63;
      *(ushort4*)(kvbf + ((size_t)b*SK + k)*KD + 512 + rr) = f2bf4(v);
    }
  }
}

// ------- L2: [bx<576] proj2 (self-reduced act from P1) | [else] reduce1 ------
__global__ __launch_bounds__(256)
void k_proj2r1(const float* __restrict__ Wuq,
               const float* __restrict__ Wqr,
               float* __restrict__ ws,
               float* __restrict__ out_ckv,
               float* __restrict__ out_kr) {
  __shared__ float4 red_s[4][NB][64];
  __shared__ float act_s[NB][64];
  unsigned short* kvbf = (unsigned short*)(ws + WS_KVBF);
  const int bx = blockIdx.x;
  const int tid = threadIdx.x;
  if (bx < 576) {
    const int gx = bx % 24, gy = bx / 24;
    {
      const int b = tid >> 6, i = tid & 63;
      const int k = gy * 64 + i;
      const float* base = ws + WS_P1 + (size_t)b*2112 + 512 + k;
      float s = 0.f;
      #pragma unroll 8
      for (int p = 0; p < NP1; ++p) s += base[(size_t)p*NB*2112];
      act_s[b][i] = s;
    }
    __syncthreads();
    const int lane = tid & 63, ksub = tid >> 6;
    const int col4 = gx * 64 + lane;
    const float* W; int C4, wcol4;
    if (col4 < 1024) { W = Wuq; C4 = 1024; wcol4 = col4; }
    else             { W = Wqr; C4 = 512;  wcol4 = col4 - 1024; }
    const float4* wp = (const float4*)W + (size_t)(gy*64 + ksub*16) * C4 + wcol4;
    float4 acc[NB] = {};
    #pragma unroll
    for (int i = 0; i < 16; ++i) {
      float4 w4 = wp[(size_t)i * C4];
      #pragma unroll
      for (int b = 0; b < NB; ++b) fma4(acc[b], act_s[b][ksub*16 + i], w4);
    }
    #pragma unroll
    for (int b = 0; b < NB; ++b) red_s[ksub][b][lane] = acc[b];
    __syncthreads();
    if (ksub == 0) {
      #pragma unroll
      for (int b = 0; b < NB; ++b) {
        float4 s = red_s[0][b][lane];
        #pragma unroll
        for (int j = 1; j < 4; ++j) {
          float4 v = red_s[j][b][lane];
          s.x += v.x; s.y += v.y; s.z += v.z; s.w += v.w;
        }
        *(float4*)(ws + WS_P2 + (size_t)(gy*NB + b)*6144 + col4*4) = s;
      }
    }
  } else {
    const int w = (bx - 576) * 256 + tid;
    if (w >= 528*NB) return;
    const int b = w / 528, col4 = w % 528;
    float4 s = {};
    #pragma unroll 8
    for (int p = 0; p < NP1; ++p) {
      float4 v = *(const float4*)(ws + WS_P1 + ((size_t)(p*NB + b)*528 + col4)*4);
      s.x += v.x; s.y += v.y; s.z += v.z; s.w += v.w;
    }
    if (col4 < 128) {
      *(float4*)(ws + WS_CKV + b*CKV + col4*4) = s;
      *(float4*)(out_ckv + (size_t)b*SK*CKV + (size_t)SS*CKV + col4*4) = s;
      *(ushort4*)(kvbf + ((size_t)b*SK + SS)*KD + col4*4) = f2bf4(s);
    } else if (col4 < 512) {
      *(float4*)(ws + WS_CQ + b*CQ + (col4 - 128)*4) = s;
    } else {
      const int c0 = (col4 - 512) * 4;
      const double LN1E4 = 9.210340371976184;
      int i0 = c0 >> 1;
      double a0 = 4096.0 * exp(-(double)i0 / 32.0 * LN1E4);
      double a1 = 4096.0 * exp(-(double)(i0 + 1) / 32.0 * LN1E4);
      float c0f = (float)cos(a0), s0f = (float)sin(a0);
      float c1f = (float)cos(a1), s1f = (float)sin(a1);
      float4 o;
      o.x = s.x*c0f - s.y*s0f;  o.y = s.x*s0f + s.y*c0f;
      o.z = s.z*c1f - s.w*s1f;  o.w = s.z*s1f + s.w*c1f;
      *(float4*)(ws + WS_KROPE + b*RD + c0) = o;
      *(float4*)(out_kr + (size_t)b*SK*RD + (size_t)SS*RD + c0) = o;
      *(ushort4*)(kvbf + ((size_t)b*SK + SS)*KD + 512 + c0) = f2bf4(o);
    }
  }
}

// -------- L3: q_abs = q_C @ W_UK^T (×SCALE) + bf16 q; q_R RoPE ---------------
__global__ __launch_bounds__(256)
void k_absorb_rope(const float* __restrict__ Wuk,
                   float* __restrict__ ws) {
  unsigned short* qbf = (unsigned short*)(ws + WS_QBF);
  const int bid = blockIdx.x, tid = threadIdx.x;
  if (bid < 256) {
    const int h = bid >> 3, cq = bid & 7;
    __shared__ float qc_s[NB][HD];
    __shared__ float part_s[NB][256];
    for (int e = tid; e < NB*HD; e += 256) {
      int b = e >> 7, d = e & 127;
      float v = 0.f;
      #pragma unroll
      for (int p = 0; p < NP2; ++p)
        v += ws[WS_P2 + (size_t)(p*NB + b)*6144 + h*HD + d];
      qc_s[b][d] = v;
    }
    __syncthreads();
    const int c = cq*64 + (tid & 63);
    const int dg = tid >> 6;
    const float4* wrow = (const float4*)(Wuk + (size_t)c*(NH*HD) + h*HD + dg*32);
    float acc[NB] = {0,0,0,0};
    #pragma unroll
    for (int d4 = 0; d4 < 8; ++d4) {
      float4 w4 = wrow[d4];
      #pragma unroll
      for (int b = 0; b < NB; ++b)
        acc[b] += dot4(w4, *(const float4*)&qc_s[b][dg*32 + d4*4]);
    }
    #pragma unroll
    for (int b = 0; b < NB; ++b) part_s[b][tid] = acc[b];
    __syncthreads();
    if (tid < 64) {
      #pragma unroll
      for (int b = 0; b < NB; ++b) {
        float v = (part_s[b][tid] + part_s[b][tid+64] + part_s[b][tid+128] + part_s[b][tid+192]) * SCALE_F;
        ws[WS_QABS + (size_t)(b*NH + h)*CKV + cq*64 + tid] = v;
        qbf[(size_t)(b*NH + h)*KD + cq*64 + tid] = f2bf(v);
      }
    }
  } else {
    const int b = bid - 256;
    const double LN1E4 = 9.210340371976184;
    for (int pid = tid; pid < NH*32; pid += 256) {
      int h = pid >> 5, i = pid & 31;
      float x1 = 0.f, x2 = 0.f;
      #pragma unroll
      for (int p = 0; p < NP2; ++p) {
        const float* base = ws + WS_P2 + (size_t)(p*NB + b)*6144 + 4096 + h*RD + 2*i;
        x1 += base[0]; x2 += base[1];
      }
      double ang = 4096.0 * exp(-(double)i / 32.0 * LN1E4);
      float cs = (float)cos(ang), sn = (float)sin(ang);
      float o0 = (x1*cs - x2*sn) * SCALE_F;
      float o1 = (x1*sn + x2*cs) * SCALE_F;
      ws[WS_QROPE + (b*NH + h)*RD + 2*i]     = o0;
      ws[WS_QROPE + (b*NH + h)*RD + 2*i + 1] = o1;
      qbf[(size_t)(b*NH + h)*KD + 512 + 2*i]     = f2bf(o0);
      qbf[(size_t)(b*NH + h)*KD + 512 + 2*i + 1] = f2bf(o1);
    }
  }
}

// ---------------- L4: scores via MFMA bf16 ----------------------------------
// block: 32 heads × 32 keys × full K=576; 4 waves = 2 m-tiles × 2 n-tiles;
// 18 × mfma_f32_16x16x32_bf16 per wave. grid (129, 4). LDS 73 KB -> 2/CU.
__global__ __launch_bounds__(256)
void k_scores_mfma(float* __restrict__ ws) {
  __shared__ unsigned short q_s[32 * QKB_STR];
  __shared__ unsigned short kv_s[32 * QKB_STR];
  const unsigned short* kvbf = (const unsigned short*)(ws + WS_KVBF);
  const unsigned short* qbf  = (const unsigned short*)(ws + WS_QBF);
  const int tid = threadIdx.x;
  const int b  = blockIdx.y;
  const int k0 = blockIdx.x * 32;
  // ---- stage q (32 heads × 576) and kv (32 keys × 576): 8 thr/row, 9 units
  {
    const int r = tid >> 3, u0 = tid & 7;
    const unsigned short* qsrc = qbf + (size_t)(b*NH + r)*KD;
    const int k = k0 + r;
    const unsigned short* ksrc = (k <= SS) ? (kvbf + ((size_t)b*SK + k)*KD) : nullptr;
    #pragma unroll
    for (int j = 0; j < 9; ++j) {
      int u = (u0 + 8*j) * 8;   // bf16 offset, 16B units
      *(uint4*)&q_s[r*QKB_STR + u] = *(const uint4*)(qsrc + u);
      uint4 kvv = {0u, 0u, 0u, 0u};
      if (ksrc) kvv = *(const uint4*)(ksrc + u);
      *(uint4*)&kv_s[r*QKB_STR + u] = kvv;
    }
  }
  __syncthreads();
  const int wid = tid >> 6, lane = tid & 63;
  const int m0 = (wid & 1) * 16;    // head tile
  const int n0 = (wid >> 1) * 16;   // key tile
  const int l15 = lane & 15, lq = lane >> 4;
  const unsigned short* arow = &q_s[(m0 + l15)*QKB_STR + lq*8];
  const unsigned short* brow = &kv_s[(n0 + l15)*QKB_STR + lq*8];
  f32x4 acc = {0.f, 0.f, 0.f, 0.f};
  #pragma unroll
  for (int ks = 0; ks < 18; ++ks) {
    short8v a = *(const short8v*)(arow + ks*32);
    short8v bb = *(const short8v*)(brow + ks*32);
    acc = __builtin_amdgcn_mfma_f32_16x16x32_bf16(a, bb, acc, 0, 0, 0);
  }
  const int key = k0 + n0 + l15;
  if (key <= SS) {
    #pragma unroll
    for (int r = 0; r < 4; ++r) {
      int h = m0 + lq*4 + r;
      ws[WS_SCA + (size_t)(b*NH + h)*SKP + key] = acc[r];
    }
  }
}

// ---------------- L5: softmax(SCA + mask) -> probs in SCA -------------------
__global__ __launch_bounds__(256)
void k_softmax(const float* __restrict__ mask, float* __restrict__ ws) {
  __shared__ float red[256];
  const int tid = threadIdx.x;
  const int b = blockIdx.x >> 5;
  float* sa = ws + WS_SCA + (size_t)blockIdx.x * SKP;
  const float* mrow = mask + (size_t)b * SK;
  float v[17];
  float m = -INFINITY;
  #pragma unroll
  for (int r = 0; r < 17; ++r) {
    int k = tid + r*256;
    v[r] = (k < SK) ? (sa[k] + mrow[k] * (-1e9f)) : -INFINITY;
    m = fmaxf(m, v[r]);
  }
  red[tid] = m; __syncthreads();
  for (int st = 128; st > 0; st >>= 1) {
    if (tid < st) red[tid] = fmaxf(red[tid], red[tid+st]);
    __syncthreads();
  }
  m = red[0]; __syncthreads();
  float e[17];
  float l = 0.f;
  #pragma unroll
  for (int r = 0; r < 17; ++r) {
    int k = tid + r*256;
    e[r] = (k < SK) ? __expf(v[r] - m) : 0.f;
    l += e[r];
  }
  red[tid] = l; __syncthreads();
  for (int st = 128; st > 0; st >>= 1) {
    if (tid < st) red[tid] += red[tid+st];
    __syncthreads();
  }
  float inv = 1.f / red[0];
  #pragma unroll
  for (int r = 0; r < 17; ++r) {
    int k = tid + r*256;
    if (k < SK) sa[k] = e[r] * inv;
  }
}

// ---------------- L6: o_latent partials — LDS-staged probs ------------------
__global__ __launch_bounds__(256)
void k_pv(const float* __restrict__ kv_cache, float* __restrict__ ws) {
  __shared__ float p_s[32][132];
  const int tid = threadIdx.x;
  const int c4 = tid & 15, hg = tid >> 4;
  const int b  = blockIdx.z;
  const int c  = blockIdx.y * 64 + c4 * 4;
  const int k0 = blockIdx.x * 128;
  #pragma unroll
  for (int j = 0; j < 4; ++j) {
    int e = tid + j*256;
    int h = e >> 5, k4 = e & 31;
    *(float4*)&p_s[h][k4*4] =
        *(const float4*)(ws + WS_SCA + (size_t)(b*NH + h)*SKP + k0 + k4*4);
  }
  __syncthreads();
  const float* kvp = kv_cache + ((size_t)b*SS + k0)*CKV + c;
  float4 acc0 = {}, acc1 = {};
  #pragma unroll 4
  for (int kk = 0; kk < 128; kk += 4) {
    float4 kv4[4];
    #pragma unroll
    for (int j = 0; j < 4; ++j)
      kv4[j] = *(const float4*)(kvp + (size_t)(kk + j)*CKV);
    float4 p4a = *(const float4*)&p_s[hg][kk];
    float4 p4b = *(const float4*)&p_s[hg + 16][kk];
    fma4(acc0, p4a.x, kv4[0]); fma4(acc1, p4b.x, kv4[0]);
    fma4(acc0, p4a.y, kv4[1]); fma4(acc1, p4b.y, kv4[1]);
    fma4(acc0, p4a.z, kv4[2]); fma4(acc1, p4b.z, kv4[2]);
    fma4(acc0, p4a.w, kv4[3]); fma4(acc1, p4b.w, kv4[3]);
  }
  if (blockIdx.x == NPV - 1) {
    float4 kv = *(const float4*)(ws + WS_CKV + b*CKV + c);
    float pa = ws[WS_SCA + (size_t)(b*NH + hg)*SKP + SS];
    float pb = ws[WS_SCA + (size_t)(b*NH + hg + 16)*SKP + SS];
    fma4(acc0, pa, kv);
    fma4(acc1, pb, kv);
  }
  *(float4*)(ws + WS_OPART + (((size_t)blockIdx.x*NB + b)*NH + hg)*CKV + c) = acc0;
  *(float4*)(ws + WS_OPART + (((size_t)blockIdx.x*NB + b)*NH + hg + 16)*CKV + c) = acc1;
}

// ------- L7: uv with OPART self-reduce pre-phase -----------------------------
__global__ __launch_bounds__(256)
void k_uv2(const float* __restrict__ Wuv, float* __restrict__ ws) {
  __shared__ float4 red_s[4][NB][64];
  __shared__ float ol_s[NB][2][32];
  const int tid = threadIdx.x;
  const int x = blockIdx.x & 15, y = blockIdx.x >> 4;
  {
    const int b = tid >> 6, hh = (tid >> 5) & 1, ci = tid & 31;
    const float* base = ws + WS_OPART + ((size_t)b*NH + (2*x + hh))*CKV + y*32 + ci;
    float s = 0.f;
    #pragma unroll 8
    for (int p = 0; p < NPV; ++p) s += base[(size_t)p*(NB*NH*CKV)];
    ol_s[b][hh][ci] = s;
  }
  __syncthreads();
  const int lane = tid & 63, csub = tid >> 6;
  const int col4 = x * 64 + lane;
  const int hh = (col4 >> 5) & 1;
  const float4* wp = (const float4*)Wuv + (size_t)(y*32 + csub*8) * 1024 + col4;
  float4 acc[NB] = {};
  #pragma unroll
  for (int i = 0; i < 8; ++i) {
    float4 w4 = wp[(size_t)i * 1024];
    #pragma unroll
    for (int b = 0; b < NB; ++b)
      fma4(acc[b], ol_s[b][hh][csub*8 + i], w4);
  }
  #pragma unroll
  for (int b = 0; b < NB; ++b) red_s[csub][b][lane] = acc[b];
  __syncthreads();
  if (csub == 0) {
    #pragma unroll
    for (int b = 0; b < NB; ++b) {
      float4 s = red_s[0][b][lane];
      #pragma unroll
      for (int j = 1; j < 4; ++j) {
        float4 v = red_s[j][b][lane];
        s.x += v.x; s.y += v.y; s.z += v.z; s.w += v.w;
      }
      *(float4*)(ws + WS_UVPART + (size_t)(y*NB + b)*HID + col4*4) = s;
    }
  }
}

// ------- L8: wo with UVPART self-reduce pre-phase ----------------------------
__global__ __launch_bounds__(256)
void k_wo2(const float* __restrict__ Wo, float* __restrict__ ws) {
  __shared__ float4 red_s[4][NB][64];
  __shared__ float at_s[NB][128];
  const int tid = threadIdx.x;
  const int x = blockIdx.x & 15, y = blockIdx.x >> 4;
  {
    const int b = tid >> 6, q = tid & 63;
    #pragma unroll
    for (int e = 0; e < 2; ++e) {
      int idx = q*2 + e;
      const float* base = ws + WS_UVPART + (size_t)b*HID + y*128 + idx;
      float s = 0.f;
      #pragma unroll
      for (int p = 0; p < NUV; ++p) s += base[(size_t)p*(NB*HID)];
      at_s[b][idx] = s;
    }
  }
  __syncthreads();
  const int lane = tid & 63, ksub = tid >> 6;
  const int col4 = x * 64 + lane;
  const float4* wp = (const float4*)Wo + (size_t)(y*128 + ksub*32) * 1024 + col4;
  float4 acc[NB] = {};
  #pragma unroll 8
  for (int i = 0; i < 32; ++i) {
    float4 w4 = wp[(size_t)i * 1024];
    #pragma unroll
    for (int b = 0; b < NB; ++b)
      fma4(acc[b], at_s[b][ksub*32 + i], w4);
  }
  #pragma unroll
  for (int b = 0; b < NB; ++b) red_s[ksub][b][lane] = acc[b];
  __syncthreads();
  if (ksub == 0) {
    #pragma unroll
    for (int b = 0; b < NB; ++b) {
      float4 s = red_s[0][b][lane];
      #pragma unroll
      for (int j = 1; j < 4; ++j) {
        float4 v = red_s[j][b][lane];
        s.x += v.x; s.y += v.y; s.z += v.z; s.w += v.w;
      }
      *(float4*)(ws + WS_WOPART + (size_t)(y*NB + b)*HID + col4*4) = s;
    }
  }
}

// ---------------- L9: out = sum_p WOPART[p] ----------------------------------
__global__ __launch_bounds__(256)
void k_reduce5(const float* __restrict__ ws, float* __restrict__ out) {
  const int idx = blockIdx.x * 256 + threadIdx.x;
  float4 s = {};
  #pragma unroll 8
  for (int p = 0; p < NWO; ++p) {
    float4 v = *(const float4*)(ws + WS_WOPART + (size_t)p*(NB*HID) + (size_t)idx*4);
    s.x += v.x; s.y += v.y; s.z += v.z; s.w += v.w;
  }
  *(float4*)(out + (size_t)idx*4) = s;
}

extern "C" void kernel_launch(void* const* d_in, const int* in_sizes, int n_in,
                              void* d_out, int out_size, void* d_ws, size_t ws_size,
                              hipStream_t stream) {
  (void)in_sizes; (void)n_in; (void)out_size; (void)ws_size;
  const float* hidden = (const float*)d_in[0];
  const float* mask   = (const float*)d_in[1];
  const float* ckv_c  = (const float*)d_in[2];
  const float* kr_c   = (const float*)d_in[3];
  const float* Wdkv   = (const float*)d_in[4];
  const float* Wuk    = (const float*)d_in[5];
  const float* Wuv    = (const float*)d_in[6];
  const float* Wdq    = (const float*)d_in[7];
  const float* Wuq    = (const float*)d_in[8];
  const float* Wqr    = (const float*)d_in[9];
  const float* Wkr    = (const float*)d_in[10];
  const float* Wo     = (const float*)d_in[11];
  float* out = (float*)d_out;
  float* ws  = (float*)d_ws;
  float* out_ckv = out + NB*HID;
  float* out_kr  = out + NB*HID + (size_t)NB*SK*CKV;

  k_proj1copy<<<9792, 256, 0, stream>>>(hidden, Wdkv, Wdq, Wkr, ws,
                                        (const float4*)ckv_c, (const float4*)kr_c,
                                        (float4*)out_ckv, (float4*)out_kr);
  k_proj2r1<<<585, 256, 0, stream>>>(Wuq, Wqr, ws, out_ckv, out_kr);
  k_absorb_rope<<<260, 256, 0, stream>>>(Wuk, ws);
  k_scores_mfma<<<dim3(129, 4), 256, 0, stream>>>(ws);
  k_softmax<<<NB*NH, 256, 0, stream>>>(mask, ws);
  k_pv<<<dim3(NPV, 8, 4), 256, 0, stream>>>(ckv_c, ws);
  k_uv2<<<256, 256, 0, stream>>>(Wuv, ws);
  k_wo2<<<512, 256, 0, stream>>>(Wo, ws);
  k_reduce5<<<16, 256, 0, stream>>>(ws, out);
}

// Round 15
// 110.663 us; speedup vs baseline: 1.2756x; 1.0178x over previous
//
#include <hip/hip_runtime.h>
#include <math.h>

#define NB 4
#define HID 4096
#define CKV 512
#define CQ 1536
#define NH 32
#define HD 128
#define RD 64
#define SS 4096
#define SK 4097
#define SKP 4100  // padded f32 scores row stride

#define SCALE_F 0.07216878364870322f  // 1/sqrt(192)

#define NP1 64   // proj1 k-partials
#define NP2 24   // proj2 k-partials
#define NPV 32   // pv key-chunks (128 keys)
#define NUV 16   // uv c-partials
#define NWO 32   // wo k-partials

#define KD   576      // latent 512 + rope 64, contiguous bf16 rows
#define QKB_STR 584   // LDS bf16 row stride (16B-aligned, +8 pad)
#define PBF_STR 4104  // bf16 probs row stride (16B-aligned)

typedef __attribute__((ext_vector_type(8))) short short8v;
typedef __attribute__((ext_vector_type(4))) float f32x4;

// workspace offsets (floats). ALL regions disjoint (ws is 256 MB).
enum : int {
  WS_QABS  = 0,                        // [NB][NH][CKV] f32, pre-scaled
  WS_QROPE = WS_QABS + NB*NH*CKV,      // [NB][NH][RD]  f32, pre-scaled
  WS_KROPE = WS_QROPE + NB*NH*RD,      // [NB][RD]
  WS_CKV   = WS_KROPE + NB*RD,         // [NB][CKV]
  WS_CQ    = WS_CKV + NB*CKV,          // [NB][CQ]
  WS_SCA   = WS_CQ + NB*CQ,            // [NB][NH][SKP] raw scores (f32)
  WS_P1    = WS_SCA + NB*NH*SKP,       // [NP1][NB][528 f4]
  WS_P2    = WS_P1 + NP1*NB*528*4,     // [NP2][NB][6144]
  WS_OPART = WS_P2 + NP2*NB*6144,      // [NPV][NB][NH][CKV]
  WS_UVPART= WS_OPART + NPV*NB*NH*CKV, // [NUV][NB][HID]
  WS_WOPART= WS_UVPART + NUV*NB*HID,   // [NWO][NB][HID]
  WS_KVBF  = WS_WOPART + NWO*NB*HID,   // bf16 [NB][SK][576]
  WS_QBF   = WS_KVBF + (NB*SK*KD)/2,   // bf16 [NB][NH][576]
  WS_PBF   = WS_QBF + (NB*NH*KD)/2,    // bf16 [NB][NH][PBF_STR] probs
  WS_TOTAL = WS_PBF + (NB*NH*PBF_STR)/2
};

__device__ inline void fma4(float4& a, float s, const float4& v) {
  a.x += s*v.x; a.y += s*v.y; a.z += s*v.z; a.w += s*v.w;
}
__device__ inline float dot4(const float4& a, const float4& b) {
  return a.x*b.x + a.y*b.y + a.z*b.z + a.w*b.w;
}
__device__ inline unsigned short f2bf(float f) {
  union { float f; unsigned int u; } v; v.f = f;
  unsigned int r = v.u + 0x7FFFu + ((v.u >> 16) & 1u);
  return (unsigned short)(r >> 16);
}
__device__ inline ushort4 f2bf4(float4 v) {
  ushort4 r; r.x = f2bf(v.x); r.y = f2bf(v.y); r.z = f2bf(v.z); r.w = f2bf(v.w);
  return r;
}
__device__ inline float bf2f(unsigned short u) {
  union { unsigned int u; float f; } v; v.u = ((unsigned int)u) << 16;
  return v.f;
}
__device__ inline float4 bf2f4(ushort4 u) {
  float4 r; r.x = bf2f(u.x); r.y = bf2f(u.y); r.z = bf2f(u.z); r.w = bf2f(u.w);
  return r;
}

// ------- L1: [bx<576] proj1 -> P1 partials | [else] cache copy + bf16 copy --
__global__ __launch_bounds__(256)
void k_proj1copy(const float* __restrict__ hidden,
                 const float* __restrict__ Wdkv,
                 const float* __restrict__ Wdq,
                 const float* __restrict__ Wkr,
                 float* __restrict__ ws,
                 const float4* __restrict__ src_ckv,
                 const float4* __restrict__ src_kr,
                 float4* __restrict__ dst_ckv,
                 float4* __restrict__ dst_kr) {
  __shared__ float4 red_s[4][NB][64];
  unsigned short* kvbf = (unsigned short*)(ws + WS_KVBF);
  const int bx = blockIdx.x;
  if (bx < 576) {
    const int gx = bx % 9, gy = bx / 9;
    const int lane = threadIdx.x & 63, ksub = threadIdx.x >> 6;
    const int col4 = gx * 64 + lane;
    const int k0 = gy * 64 + ksub * 16;
    const bool valid = col4 < 528;
    float4 acc[NB] = {};
    if (valid) {
      const float* W; int C4, wcol4;
      if (col4 < 128)      { W = Wdkv; C4 = 128; wcol4 = col4; }
      else if (col4 < 512) { W = Wdq;  C4 = 384; wcol4 = col4 - 128; }
      else                 { W = Wkr;  C4 = 16;  wcol4 = col4 - 512; }
      const float4* wp = (const float4*)W + (size_t)k0 * C4 + wcol4;
      #pragma unroll
      for (int i = 0; i < 16; ++i) {
        float4 w4 = wp[(size_t)i * C4];
        #pragma unroll
        for (int b = 0; b < NB; ++b) fma4(acc[b], hidden[b*HID + k0 + i], w4);
      }
    }
    #pragma unroll
    for (int b = 0; b < NB; ++b) red_s[ksub][b][lane] = acc[b];
    __syncthreads();
    if (ksub == 0 && valid) {
      #pragma unroll
      for (int b = 0; b < NB; ++b) {
        float4 s = red_s[0][b][lane];
        #pragma unroll
        for (int j = 1; j < 4; ++j) {
          float4 v = red_s[j][b][lane];
          s.x += v.x; s.y += v.y; s.z += v.z; s.w += v.w;
        }
        *(float4*)(ws + WS_P1 + ((size_t)(gy*NB + b)*528 + col4)*4) = s;
      }
    }
  } else {
    const int bxc = bx - 576;
    if (bxc < 8192) {
      int b = bxc >> 11;
      int idx = (bxc & 2047) * 256 + threadIdx.x;
      float4 v = src_ckv[(size_t)b*(SS*CKV/4) + idx];
      dst_ckv[(size_t)b*(SK*CKV/4) + idx] = v;
      int off = idx * 4;
      int k = off >> 9, c = off & 511;
      *(ushort4*)(kvbf + ((size_t)b*SK + k)*KD + c) = f2bf4(v);
    } else {
      int bx2 = bxc - 8192;
      int b = bx2 >> 8;
      int idx = (bx2 & 255) * 256 + threadIdx.x;
      float4 v = src_kr[(size_t)b*(SS*RD/4) + idx];
      dst_kr[(size_t)b*(SK*RD/4) + idx] = v;
      int off = idx * 4;
      int k = off >> 6, rr = off & 63;
      *(ushort4*)(kvbf + ((size_t)b*SK + k)*KD + 512 + rr) = f2bf4(v);
    }
  }
}

// ------- L2: [bx<576] proj2 (self-reduced act from P1) | [else] reduce1 ------
__global__ __launch_bounds__(256)
void k_proj2r1(const float* __restrict__ Wuq,
               const float* __restrict__ Wqr,
               float* __restrict__ ws,
               float* __restrict__ out_ckv,
               float* __restrict__ out_kr) {
  __shared__ float4 red_s[4][NB][64];
  __shared__ float act_s[NB][64];
  unsigned short* kvbf = (unsigned short*)(ws + WS_KVBF);
  const int bx = blockIdx.x;
  const int tid = threadIdx.x;
  if (bx < 576) {
    const int gx = bx % 24, gy = bx / 24;
    {
      const int b = tid >> 6, i = tid & 63;
      const int k = gy * 64 + i;
      const float* base = ws + WS_P1 + (size_t)b*2112 + 512 + k;
      float s = 0.f;
      #pragma unroll 8
      for (int p = 0; p < NP1; ++p) s += base[(size_t)p*NB*2112];
      act_s[b][i] = s;
    }
    __syncthreads();
    const int lane = tid & 63, ksub = tid >> 6;
    const int col4 = gx * 64 + lane;
    const float* W; int C4, wcol4;
    if (col4 < 1024) { W = Wuq; C4 = 1024; wcol4 = col4; }
    else             { W = Wqr; C4 = 512;  wcol4 = col4 - 1024; }
    const float4* wp = (const float4*)W + (size_t)(gy*64 + ksub*16) * C4 + wcol4;
    float4 acc[NB] = {};
    #pragma unroll
    for (int i = 0; i < 16; ++i) {
      float4 w4 = wp[(size_t)i * C4];
      #pragma unroll
      for (int b = 0; b < NB; ++b) fma4(acc[b], act_s[b][ksub*16 + i], w4);
    }
    #pragma unroll
    for (int b = 0; b < NB; ++b) red_s[ksub][b][lane] = acc[b];
    __syncthreads();
    if (ksub == 0) {
      #pragma unroll
      for (int b = 0; b < NB; ++b) {
        float4 s = red_s[0][b][lane];
        #pragma unroll
        for (int j = 1; j < 4; ++j) {
          float4 v = red_s[j][b][lane];
          s.x += v.x; s.y += v.y; s.z += v.z; s.w += v.w;
        }
        *(float4*)(ws + WS_P2 + (size_t)(gy*NB + b)*6144 + col4*4) = s;
      }
    }
  } else {
    const int w = (bx - 576) * 256 + tid;
    if (w >= 528*NB) return;
    const int b = w / 528, col4 = w % 528;
    float4 s = {};
    #pragma unroll 8
    for (int p = 0; p < NP1; ++p) {
      float4 v = *(const float4*)(ws + WS_P1 + ((size_t)(p*NB + b)*528 + col4)*4);
      s.x += v.x; s.y += v.y; s.z += v.z; s.w += v.w;
    }
    if (col4 < 128) {
      *(float4*)(ws + WS_CKV + b*CKV + col4*4) = s;
      *(float4*)(out_ckv + (size_t)b*SK*CKV + (size_t)SS*CKV + col4*4) = s;
      *(ushort4*)(kvbf + ((size_t)b*SK + SS)*KD + col4*4) = f2bf4(s);
    } else if (col4 < 512) {
      *(float4*)(ws + WS_CQ + b*CQ + (col4 - 128)*4) = s;
    } else {
      const int c0 = (col4 - 512) * 4;
      const double LN1E4 = 9.210340371976184;
      int i0 = c0 >> 1;
      double a0 = 4096.0 * exp(-(double)i0 / 32.0 * LN1E4);
      double a1 = 4096.0 * exp(-(double)(i0 + 1) / 32.0 * LN1E4);
      float c0f = (float)cos(a0), s0f = (float)sin(a0);
      float c1f = (float)cos(a1), s1f = (float)sin(a1);
      float4 o;
      o.x = s.x*c0f - s.y*s0f;  o.y = s.x*s0f + s.y*c0f;
      o.z = s.z*c1f - s.w*s1f;  o.w = s.z*s1f + s.w*c1f;
      *(float4*)(ws + WS_KROPE + b*RD + c0) = o;
      *(float4*)(out_kr + (size_t)b*SK*RD + (size_t)SS*RD + c0) = o;
      *(ushort4*)(kvbf + ((size_t)b*SK + SS)*KD + 512 + c0) = f2bf4(o);
    }
  }
}

// -------- L3: q_abs = q_C @ W_UK^T (×SCALE) + bf16 q; q_R RoPE ---------------
__global__ __launch_bounds__(256)
void k_absorb_rope(const float* __restrict__ Wuk,
                   float* __restrict__ ws) {
  unsigned short* qbf = (unsigned short*)(ws + WS_QBF);
  const int bid = blockIdx.x, tid = threadIdx.x;
  if (bid < 256) {
    const int h = bid >> 3, cq = bid & 7;
    __shared__ float qc_s[NB][HD];
    __shared__ float part_s[NB][256];
    for (int e = tid; e < NB*HD; e += 256) {
      int b = e >> 7, d = e & 127;
      float v = 0.f;
      #pragma unroll
      for (int p = 0; p < NP2; ++p)
        v += ws[WS_P2 + (size_t)(p*NB + b)*6144 + h*HD + d];
      qc_s[b][d] = v;
    }
    __syncthreads();
    const int c = cq*64 + (tid & 63);
    const int dg = tid >> 6;
    const float4* wrow = (const float4*)(Wuk + (size_t)c*(NH*HD) + h*HD + dg*32);
    float acc[NB] = {0,0,0,0};
    #pragma unroll
    for (int d4 = 0; d4 < 8; ++d4) {
      float4 w4 = wrow[d4];
      #pragma unroll
      for (int b = 0; b < NB; ++b)
        acc[b] += dot4(w4, *(const float4*)&qc_s[b][dg*32 + d4*4]);
    }
    #pragma unroll
    for (int b = 0; b < NB; ++b) part_s[b][tid] = acc[b];
    __syncthreads();
    if (tid < 64) {
      #pragma unroll
      for (int b = 0; b < NB; ++b) {
        float v = (part_s[b][tid] + part_s[b][tid+64] + part_s[b][tid+128] + part_s[b][tid+192]) * SCALE_F;
        ws[WS_QABS + (size_t)(b*NH + h)*CKV + cq*64 + tid] = v;
        qbf[(size_t)(b*NH + h)*KD + cq*64 + tid] = f2bf(v);
      }
    }
  } else {
    const int b = bid - 256;
    const double LN1E4 = 9.210340371976184;
    for (int pid = tid; pid < NH*32; pid += 256) {
      int h = pid >> 5, i = pid & 31;
      float x1 = 0.f, x2 = 0.f;
      #pragma unroll
      for (int p = 0; p < NP2; ++p) {
        const float* base = ws + WS_P2 + (size_t)(p*NB + b)*6144 + 4096 + h*RD + 2*i;
        x1 += base[0]; x2 += base[1];
      }
      double ang = 4096.0 * exp(-(double)i / 32.0 * LN1E4);
      float cs = (float)cos(ang), sn = (float)sin(ang);
      float o0 = (x1*cs - x2*sn) * SCALE_F;
      float o1 = (x1*sn + x2*cs) * SCALE_F;
      ws[WS_QROPE + (b*NH + h)*RD + 2*i]     = o0;
      ws[WS_QROPE + (b*NH + h)*RD + 2*i + 1] = o1;
      qbf[(size_t)(b*NH + h)*KD + 512 + 2*i]     = f2bf(o0);
      qbf[(size_t)(b*NH + h)*KD + 512 + 2*i + 1] = f2bf(o1);
    }
  }
}

// ---------------- L4: scores via MFMA bf16 (proven R14 form) -----------------
__global__ __launch_bounds__(256)
void k_scores_mfma(float* __restrict__ ws) {
  __shared__ unsigned short q_s[32 * QKB_STR];
  __shared__ unsigned short kv_s[32 * QKB_STR];
  const unsigned short* kvbf = (const unsigned short*)(ws + WS_KVBF);
  const unsigned short* qbf  = (const unsigned short*)(ws + WS_QBF);
  const int tid = threadIdx.x;
  const int b  = blockIdx.y;
  const int k0 = blockIdx.x * 32;
  {
    const int r = tid >> 3, u0 = tid & 7;
    const unsigned short* qsrc = qbf + (size_t)(b*NH + r)*KD;
    const int k = k0 + r;
    const unsigned short* ksrc = (k <= SS) ? (kvbf + ((size_t)b*SK + k)*KD) : nullptr;
    #pragma unroll
    for (int j = 0; j < 9; ++j) {
      int u = (u0 + 8*j) * 8;
      *(uint4*)&q_s[r*QKB_STR + u] = *(const uint4*)(qsrc + u);
      uint4 kvv = {0u, 0u, 0u, 0u};
      if (ksrc) kvv = *(const uint4*)(ksrc + u);
      *(uint4*)&kv_s[r*QKB_STR + u] = kvv;
    }
  }
  __syncthreads();
  const int wid = tid >> 6, lane = tid & 63;
  const int m0 = (wid & 1) * 16;
  const int n0 = (wid >> 1) * 16;
  const int l15 = lane & 15, lq = lane >> 4;
  const unsigned short* arow = &q_s[(m0 + l15)*QKB_STR + lq*8];
  const unsigned short* brow = &kv_s[(n0 + l15)*QKB_STR + lq*8];
  f32x4 acc = {0.f, 0.f, 0.f, 0.f};
  #pragma unroll
  for (int ks = 0; ks < 18; ++ks) {
    short8v a = *(const short8v*)(arow + ks*32);
    short8v bb = *(const short8v*)(brow + ks*32);
    acc = __builtin_amdgcn_mfma_f32_16x16x32_bf16(a, bb, acc, 0, 0, 0);
  }
  const int key = k0 + n0 + l15;
  if (key <= SS) {
    #pragma unroll
    for (int r = 0; r < 4; ++r) {
      int h = m0 + lq*4 + r;
      ws[WS_SCA + (size_t)(b*NH + h)*SKP + key] = acc[r];
    }
  }
}

// ---------------- L5: softmax(SCA + mask) -> bf16 probs in PBF ---------------
__global__ __launch_bounds__(256)
void k_softmax(const float* __restrict__ mask, float* __restrict__ ws) {
  __shared__ float red[256];
  unsigned short* pbf = (unsigned short*)(ws + WS_PBF);
  const int tid = threadIdx.x;
  const int b = blockIdx.x >> 5;
  const float* sa = ws + WS_SCA + (size_t)blockIdx.x * SKP;
  unsigned short* prow = pbf + (size_t)blockIdx.x * PBF_STR;
  const float* mrow = mask + (size_t)b * SK;
  float v[17];
  float m = -INFINITY;
  #pragma unroll
  for (int r = 0; r < 17; ++r) {
    int k = tid + r*256;
    v[r] = (k < SK) ? (sa[k] + mrow[k] * (-1e9f)) : -INFINITY;
    m = fmaxf(m, v[r]);
  }
  red[tid] = m; __syncthreads();
  for (int st = 128; st > 0; st >>= 1) {
    if (tid < st) red[tid] = fmaxf(red[tid], red[tid+st]);
    __syncthreads();
  }
  m = red[0]; __syncthreads();
  float e[17];
  float l = 0.f;
  #pragma unroll
  for (int r = 0; r < 17; ++r) {
    int k = tid + r*256;
    e[r] = (k < SK) ? __expf(v[r] - m) : 0.f;
    l += e[r];
  }
  red[tid] = l; __syncthreads();
  for (int st = 128; st > 0; st >>= 1) {
    if (tid < st) red[tid] += red[tid+st];
    __syncthreads();
  }
  float inv = 1.f / red[0];
  #pragma unroll
  for (int r = 0; r < 17; ++r) {
    int k = tid + r*256;
    if (k < SK) prow[k] = f2bf(e[r] * inv);
  }
}

// ---------------- L6: o_latent partials — bf16 probs + bf16 kv ---------------
__global__ __launch_bounds__(256)
void k_pv(float* __restrict__ ws) {
  __shared__ float p_s[32][132];
  const unsigned short* kvbf = (const unsigned short*)(ws + WS_KVBF);
  const unsigned short* pbf  = (const unsigned short*)(ws + WS_PBF);
  const int tid = threadIdx.x;
  const int c4 = tid & 15, hg = tid >> 4;
  const int b  = blockIdx.z;
  const int c  = blockIdx.y * 64 + c4 * 4;
  const int k0 = blockIdx.x * 128;
  // stage probs: 32 rows × 128 keys, bf16 -> f32
  #pragma unroll
  for (int j = 0; j < 2; ++j) {
    int u = tid + j*256;                 // ushort8-unit id, 512 total
    int h = u >> 4, c8 = u & 15;
    const unsigned short* src = pbf + (size_t)(b*NH + h)*PBF_STR + k0 + c8*8;
    ushort4 a0 = *(const ushort4*)(src);
    ushort4 a1 = *(const ushort4*)(src + 4);
    float4 f0 = bf2f4(a0), f1 = bf2f4(a1);
    *(float4*)&p_s[h][c8*8]     = f0;
    *(float4*)&p_s[h][c8*8 + 4] = f1;
  }
  __syncthreads();
  const unsigned short* kvp = kvbf + ((size_t)b*SK + k0)*KD + c;
  float4 acc0 = {}, acc1 = {};
  #pragma unroll 4
  for (int kk = 0; kk < 128; kk += 4) {
    float4 kv4[4];
    #pragma unroll
    for (int j = 0; j < 4; ++j)
      kv4[j] = bf2f4(*(const ushort4*)(kvp + (size_t)(kk + j)*KD));
    float4 p4a = *(const float4*)&p_s[hg][kk];
    float4 p4b = *(const float4*)&p_s[hg + 16][kk];
    fma4(acc0, p4a.x, kv4[0]); fma4(acc1, p4b.x, kv4[0]);
    fma4(acc0, p4a.y, kv4[1]); fma4(acc1, p4b.y, kv4[1]);
    fma4(acc0, p4a.z, kv4[2]); fma4(acc1, p4b.z, kv4[2]);
    fma4(acc0, p4a.w, kv4[3]); fma4(acc1, p4b.w, kv4[3]);
  }
  if (blockIdx.x == NPV - 1) {   // tail key k == SS
    float4 kv = bf2f4(*(const ushort4*)(kvbf + ((size_t)b*SK + SS)*KD + c));
    float pa = bf2f(pbf[(size_t)(b*NH + hg)*PBF_STR + SS]);
    float pb = bf2f(pbf[(size_t)(b*NH + hg + 16)*PBF_STR + SS]);
    fma4(acc0, pa, kv);
    fma4(acc1, pb, kv);
  }
  *(float4*)(ws + WS_OPART + (((size_t)blockIdx.x*NB + b)*NH + hg)*CKV + c) = acc0;
  *(float4*)(ws + WS_OPART + (((size_t)blockIdx.x*NB + b)*NH + hg + 16)*CKV + c) = acc1;
}

// ------- L7: uv with OPART self-reduce pre-phase -----------------------------
__global__ __launch_bounds__(256)
void k_uv2(const float* __restrict__ Wuv, float* __restrict__ ws) {
  __shared__ float4 red_s[4][NB][64];
  __shared__ float ol_s[NB][2][32];
  const int tid = threadIdx.x;
  const int x = blockIdx.x & 15, y = blockIdx.x >> 4;
  {
    const int b = tid >> 6, hh = (tid >> 5) & 1, ci = tid & 31;
    const float* base = ws + WS_OPART + ((size_t)b*NH + (2*x + hh))*CKV + y*32 + ci;
    float s = 0.f;
    #pragma unroll 8
    for (int p = 0; p < NPV; ++p) s += base[(size_t)p*(NB*NH*CKV)];
    ol_s[b][hh][ci] = s;
  }
  __syncthreads();
  const int lane = tid & 63, csub = tid >> 6;
  const int col4 = x * 64 + lane;
  const int hh = (col4 >> 5) & 1;
  const float4* wp = (const float4*)Wuv + (size_t)(y*32 + csub*8) * 1024 + col4;
  float4 acc[NB] = {};
  #pragma unroll
  for (int i = 0; i < 8; ++i) {
    float4 w4 = wp[(size_t)i * 1024];
    #pragma unroll
    for (int b = 0; b < NB; ++b)
      fma4(acc[b], ol_s[b][hh][csub*8 + i], w4);
  }
  #pragma unroll
  for (int b = 0; b < NB; ++b) red_s[csub][b][lane] = acc[b];
  __syncthreads();
  if (csub == 0) {
    #pragma unroll
    for (int b = 0; b < NB; ++b) {
      float4 s = red_s[0][b][lane];
      #pragma unroll
      for (int j = 1; j < 4; ++j) {
        float4 v = red_s[j][b][lane];
        s.x += v.x; s.y += v.y; s.z += v.z; s.w += v.w;
      }
      *(float4*)(ws + WS_UVPART + (size_t)(y*NB + b)*HID + col4*4) = s;
    }
  }
}

// ------- L8: wo with UVPART self-reduce pre-phase ----------------------------
__global__ __launch_bounds__(256)
void k_wo2(const float* __restrict__ Wo, float* __restrict__ ws) {
  __shared__ float4 red_s[4][NB][64];
  __shared__ float at_s[NB][128];
  const int tid = threadIdx.x;
  const int x = blockIdx.x & 15, y = blockIdx.x >> 4;
  {
    const int b = tid >> 6, q = tid & 63;
    #pragma unroll
    for (int e = 0; e < 2; ++e) {
      int idx = q*2 + e;
      const float* base = ws + WS_UVPART + (size_t)b*HID + y*128 + idx;
      float s = 0.f;
      #pragma unroll
      for (int p = 0; p < NUV; ++p) s += base[(size_t)p*(NB*HID)];
      at_s[b][idx] = s;
    }
  }
  __syncthreads();
  const int lane = tid & 63, ksub = tid >> 6;
  const int col4 = x * 64 + lane;
  const float4* wp = (const float4*)Wo + (size_t)(y*128 + ksub*32) * 1024 + col4;
  float4 acc[NB] = {};
  #pragma unroll 8
  for (int i = 0; i < 32; ++i) {
    float4 w4 = wp[(size_t)i * 1024];
    #pragma unroll
    for (int b = 0; b < NB; ++b)
      fma4(acc[b], at_s[b][ksub*32 + i], w4);
  }
  #pragma unroll
  for (int b = 0; b < NB; ++b) red_s[ksub][b][lane] = acc[b];
  __syncthreads();
  if (ksub == 0) {
    #pragma unroll
    for (int b = 0; b < NB; ++b) {
      float4 s = red_s[0][b][lane];
      #pragma unroll
      for (int j = 1; j < 4; ++j) {
        float4 v = red_s[j][b][lane];
        s.x += v.x; s.y += v.y; s.z += v.z; s.w += v.w;
      }
      *(float4*)(ws + WS_WOPART + (size_t)(y*NB + b)*HID + col4*4) = s;
    }
  }
}

// ---------------- L9: out = sum_p WOPART[p] ----------------------------------
__global__ __launch_bounds__(256)
void k_reduce5(const float* __restrict__ ws, float* __restrict__ out) {
  const int idx = blockIdx.x * 256 + threadIdx.x;
  float4 s = {};
  #pragma unroll 8
  for (int p = 0; p < NWO; ++p) {
    float4 v = *(const float4*)(ws + WS_WOPART + (size_t)p*(NB*HID) + (size_t)idx*4);
    s.x += v.x; s.y += v.y; s.z += v.z; s.w += v.w;
  }
  *(float4*)(out + (size_t)idx*4) = s;
}

extern "C" void kernel_launch(void* const* d_in, const int* in_sizes, int n_in,
                              void* d_out, int out_size, void* d_ws, size_t ws_size,
                              hipStream_t stream) {
  (void)in_sizes; (void)n_in; (void)out_size; (void)ws_size;
  const float* hidden = (const float*)d_in[0];
  const float* mask   = (const float*)d_in[1];
  const float* ckv_c  = (const float*)d_in[2];
  const float* kr_c   = (const float*)d_in[3];
  const float* Wdkv   = (const float*)d_in[4];
  const float* Wuk    = (const float*)d_in[5];
  const float* Wuv    = (const float*)d_in[6];
  const float* Wdq    = (const float*)d_in[7];
  const float* Wuq    = (const float*)d_in[8];
  const float* Wqr    = (const float*)d_in[9];
  const float* Wkr    = (const float*)d_in[10];
  const float* Wo     = (const float*)d_in[11];
  float* out = (float*)d_out;
  float* ws  = (float*)d_ws;
  float* out_ckv = out + NB*HID;
  float* out_kr  = out + NB*HID + (size_t)NB*SK*CKV;

  k_proj1copy<<<9792, 256, 0, stream>>>(hidden, Wdkv, Wdq, Wkr, ws,
                                        (const float4*)ckv_c, (const float4*)kr_c,
                                        (float4*)out_ckv, (float4*)out_kr);
  k_proj2r1<<<585, 256, 0, stream>>>(Wuq, Wqr, ws, out_ckv, out_kr);
  k_absorb_rope<<<260, 256, 0, stream>>>(Wuk, ws);
  k_scores_mfma<<<dim3(129, 4), 256, 0, stream>>>(ws);
  k_softmax<<<NB*NH, 256, 0, stream>>>(mask, ws);
  k_pv<<<dim3(NPV, 8, 4), 256, 0, stream>>>(ws);
  k_uv2<<<256, 256, 0, stream>>>(Wuv, ws);
  k_wo2<<<512, 256, 0, stream>>>(Wo, ws);
  k_reduce5<<<16, 256, 0, stream>>>(ws, out);
}

// Round 16
// 99.944 us; speedup vs baseline: 1.4124x; 1.1072x over previous
//
#include <hip/hip_runtime.h>
#include <math.h>

#define NB 4
#define HID 4096
#define CKV 512
#define CQ 1536
#define NH 32
#define HD 128
#define RD 64
#define SS 4096
#define SK 4097
#define SKP 4100  // padded f32 scores row stride

#define SCALE_F 0.07216878364870322f  // 1/sqrt(192)

#define NP1 64   // proj1 k-partials
#define NP2 24   // proj2 k-partials
#define NPV 32   // pv key-chunks (128 keys)
#define NUV 16   // uv c-partials
#define NWO 32   // wo k-partials

#define KD   576      // latent 512 + rope 64, contiguous bf16 rows
#define QKB_STR 584   // scores LDS bf16 row stride
#define PBF_STR 4104  // bf16 probs row stride (16B-aligned)
#define TV_STR 40     // pv kvT LDS row stride in u16 (80 B, 16B-aligned)

typedef __attribute__((ext_vector_type(8))) short short8v;
typedef __attribute__((ext_vector_type(4))) float f32x4;

// workspace offsets (floats). ALL regions disjoint (ws is 256 MB).
enum : int {
  WS_QABS  = 0,                        // [NB][NH][CKV] f32, pre-scaled
  WS_QROPE = WS_QABS + NB*NH*CKV,      // [NB][NH][RD]  f32, pre-scaled
  WS_KROPE = WS_QROPE + NB*NH*RD,      // [NB][RD]
  WS_CKV   = WS_KROPE + NB*RD,         // [NB][CKV]
  WS_CQ    = WS_CKV + NB*CKV,          // [NB][CQ]
  WS_SCA   = WS_CQ + NB*CQ,            // [NB][NH][SKP] raw scores (f32)
  WS_P1    = WS_SCA + NB*NH*SKP,       // [NP1][NB][528 f4]
  WS_P2    = WS_P1 + NP1*NB*528*4,     // [NP2][NB][6144]
  WS_OPART = WS_P2 + NP2*NB*6144,      // [NPV][NB][NH][CKV]
  WS_UVPART= WS_OPART + NPV*NB*NH*CKV, // [NUV][NB][HID]
  WS_WOPART= WS_UVPART + NUV*NB*HID,   // [NWO][NB][HID]
  WS_KVBF  = WS_WOPART + NWO*NB*HID,   // bf16 [NB][SK][576]
  WS_QBF   = WS_KVBF + (NB*SK*KD)/2,   // bf16 [NB][NH][576]
  WS_PBF   = WS_QBF + (NB*NH*KD)/2,    // bf16 [NB][NH][PBF_STR] probs
  WS_TOTAL = WS_PBF + (NB*NH*PBF_STR)/2
};

__device__ inline void fma4(float4& a, float s, const float4& v) {
  a.x += s*v.x; a.y += s*v.y; a.z += s*v.z; a.w += s*v.w;
}
__device__ inline float dot4(const float4& a, const float4& b) {
  return a.x*b.x + a.y*b.y + a.z*b.z + a.w*b.w;
}
__device__ inline unsigned short f2bf(float f) {
  union { float f; unsigned int u; } v; v.f = f;
  unsigned int r = v.u + 0x7FFFu + ((v.u >> 16) & 1u);
  return (unsigned short)(r >> 16);
}
__device__ inline ushort4 f2bf4(float4 v) {
  ushort4 r; r.x = f2bf(v.x); r.y = f2bf(v.y); r.z = f2bf(v.z); r.w = f2bf(v.w);
  return r;
}
__device__ inline float bf2f(unsigned short u) {
  union { unsigned int u; float f; } v; v.u = ((unsigned int)u) << 16;
  return v.f;
}
__device__ inline float4 bf2f4(ushort4 u) {
  float4 r; r.x = bf2f(u.x); r.y = bf2f(u.y); r.z = bf2f(u.z); r.w = bf2f(u.w);
  return r;
}

// ------- L1: [bx<576] proj1 -> P1 partials | [else] cache copy + bf16 copy --
__global__ __launch_bounds__(256)
void k_proj1copy(const float* __restrict__ hidden,
                 const float* __restrict__ Wdkv,
                 const float* __restrict__ Wdq,
                 const float* __restrict__ Wkr,
                 float* __restrict__ ws,
                 const float4* __restrict__ src_ckv,
                 const float4* __restrict__ src_kr,
                 float4* __restrict__ dst_ckv,
                 float4* __restrict__ dst_kr) {
  __shared__ float4 red_s[4][NB][64];
  unsigned short* kvbf = (unsigned short*)(ws + WS_KVBF);
  const int bx = blockIdx.x;
  if (bx < 576) {
    const int gx = bx % 9, gy = bx / 9;
    const int lane = threadIdx.x & 63, ksub = threadIdx.x >> 6;
    const int col4 = gx * 64 + lane;
    const int k0 = gy * 64 + ksub * 16;
    const bool valid = col4 < 528;
    float4 acc[NB] = {};
    if (valid) {
      const float* W; int C4, wcol4;
      if (col4 < 128)      { W = Wdkv; C4 = 128; wcol4 = col4; }
      else if (col4 < 512) { W = Wdq;  C4 = 384; wcol4 = col4 - 128; }
      else                 { W = Wkr;  C4 = 16;  wcol4 = col4 - 512; }
      const float4* wp = (const float4*)W + (size_t)k0 * C4 + wcol4;
      #pragma unroll
      for (int i = 0; i < 16; ++i) {
        float4 w4 = wp[(size_t)i * C4];
        #pragma unroll
        for (int b = 0; b < NB; ++b) fma4(acc[b], hidden[b*HID + k0 + i], w4);
      }
    }
    #pragma unroll
    for (int b = 0; b < NB; ++b) red_s[ksub][b][lane] = acc[b];
    __syncthreads();
    if (ksub == 0 && valid) {
      #pragma unroll
      for (int b = 0; b < NB; ++b) {
        float4 s = red_s[0][b][lane];
        #pragma unroll
        for (int j = 1; j < 4; ++j) {
          float4 v = red_s[j][b][lane];
          s.x += v.x; s.y += v.y; s.z += v.z; s.w += v.w;
        }
        *(float4*)(ws + WS_P1 + ((size_t)(gy*NB + b)*528 + col4)*4) = s;
      }
    }
  } else {
    const int bxc = bx - 576;
    if (bxc < 8192) {
      int b = bxc >> 11;
      int idx = (bxc & 2047) * 256 + threadIdx.x;
      float4 v = src_ckv[(size_t)b*(SS*CKV/4) + idx];
      dst_ckv[(size_t)b*(SK*CKV/4) + idx] = v;
      int off = idx * 4;
      int k = off >> 9, c = off & 511;
      *(ushort4*)(kvbf + ((size_t)b*SK + k)*KD + c) = f2bf4(v);
    } else {
      int bx2 = bxc - 8192;
      int b = bx2 >> 8;
      int idx = (bx2 & 255) * 256 + threadIdx.x;
      float4 v = src_kr[(size_t)b*(SS*RD/4) + idx];
      dst_kr[(size_t)b*(SK*RD/4) + idx] = v;
      int off = idx * 4;
      int k = off >> 6, rr = off & 63;
      *(ushort4*)(kvbf + ((size_t)b*SK + k)*KD + 512 + rr) = f2bf4(v);
    }
  }
}

// ------- L2: [bx<576] proj2 (self-reduced act from P1) | [else] reduce1 ------
__global__ __launch_bounds__(256)
void k_proj2r1(const float* __restrict__ Wuq,
               const float* __restrict__ Wqr,
               float* __restrict__ ws,
               float* __restrict__ out_ckv,
               float* __restrict__ out_kr) {
  __shared__ float4 red_s[4][NB][64];
  __shared__ float act_s[NB][64];
  unsigned short* kvbf = (unsigned short*)(ws + WS_KVBF);
  const int bx = blockIdx.x;
  const int tid = threadIdx.x;
  if (bx < 576) {
    const int gx = bx % 24, gy = bx / 24;
    {
      const int b = tid >> 6, i = tid & 63;
      const int k = gy * 64 + i;
      const float* base = ws + WS_P1 + (size_t)b*2112 + 512 + k;
      float s = 0.f;
      #pragma unroll 8
      for (int p = 0; p < NP1; ++p) s += base[(size_t)p*NB*2112];
      act_s[b][i] = s;
    }
    __syncthreads();
    const int lane = tid & 63, ksub = tid >> 6;
    const int col4 = gx * 64 + lane;
    const float* W; int C4, wcol4;
    if (col4 < 1024) { W = Wuq; C4 = 1024; wcol4 = col4; }
    else             { W = Wqr; C4 = 512;  wcol4 = col4 - 1024; }
    const float4* wp = (const float4*)W + (size_t)(gy*64 + ksub*16) * C4 + wcol4;
    float4 acc[NB] = {};
    #pragma unroll
    for (int i = 0; i < 16; ++i) {
      float4 w4 = wp[(size_t)i * C4];
      #pragma unroll
      for (int b = 0; b < NB; ++b) fma4(acc[b], act_s[b][ksub*16 + i], w4);
    }
    #pragma unroll
    for (int b = 0; b < NB; ++b) red_s[ksub][b][lane] = acc[b];
    __syncthreads();
    if (ksub == 0) {
      #pragma unroll
      for (int b = 0; b < NB; ++b) {
        float4 s = red_s[0][b][lane];
        #pragma unroll
        for (int j = 1; j < 4; ++j) {
          float4 v = red_s[j][b][lane];
          s.x += v.x; s.y += v.y; s.z += v.z; s.w += v.w;
        }
        *(float4*)(ws + WS_P2 + (size_t)(gy*NB + b)*6144 + col4*4) = s;
      }
    }
  } else {
    const int w = (bx - 576) * 256 + tid;
    if (w >= 528*NB) return;
    const int b = w / 528, col4 = w % 528;
    float4 s = {};
    #pragma unroll 8
    for (int p = 0; p < NP1; ++p) {
      float4 v = *(const float4*)(ws + WS_P1 + ((size_t)(p*NB + b)*528 + col4)*4);
      s.x += v.x; s.y += v.y; s.z += v.z; s.w += v.w;
    }
    if (col4 < 128) {
      *(float4*)(ws + WS_CKV + b*CKV + col4*4) = s;
      *(float4*)(out_ckv + (size_t)b*SK*CKV + (size_t)SS*CKV + col4*4) = s;
      *(ushort4*)(kvbf + ((size_t)b*SK + SS)*KD + col4*4) = f2bf4(s);
    } else if (col4 < 512) {
      *(float4*)(ws + WS_CQ + b*CQ + (col4 - 128)*4) = s;
    } else {
      const int c0 = (col4 - 512) * 4;
      const double LN1E4 = 9.210340371976184;
      int i0 = c0 >> 1;
      double a0 = 4096.0 * exp(-(double)i0 / 32.0 * LN1E4);
      double a1 = 4096.0 * exp(-(double)(i0 + 1) / 32.0 * LN1E4);
      float c0f = (float)cos(a0), s0f = (float)sin(a0);
      float c1f = (float)cos(a1), s1f = (float)sin(a1);
      float4 o;
      o.x = s.x*c0f - s.y*s0f;  o.y = s.x*s0f + s.y*c0f;
      o.z = s.z*c1f - s.w*s1f;  o.w = s.z*s1f + s.w*c1f;
      *(float4*)(ws + WS_KROPE + b*RD + c0) = o;
      *(float4*)(out_kr + (size_t)b*SK*RD + (size_t)SS*RD + c0) = o;
      *(ushort4*)(kvbf + ((size_t)b*SK + SS)*KD + 512 + c0) = f2bf4(o);
    }
  }
}

// -------- L3: q_abs = q_C @ W_UK^T (×SCALE) + bf16 q; q_R RoPE ---------------
__global__ __launch_bounds__(256)
void k_absorb_rope(const float* __restrict__ Wuk,
                   float* __restrict__ ws) {
  unsigned short* qbf = (unsigned short*)(ws + WS_QBF);
  const int bid = blockIdx.x, tid = threadIdx.x;
  if (bid < 256) {
    const int h = bid >> 3, cq = bid & 7;
    __shared__ float qc_s[NB][HD];
    __shared__ float part_s[NB][256];
    for (int e = tid; e < NB*HD; e += 256) {
      int b = e >> 7, d = e & 127;
      float v = 0.f;
      #pragma unroll
      for (int p = 0; p < NP2; ++p)
        v += ws[WS_P2 + (size_t)(p*NB + b)*6144 + h*HD + d];
      qc_s[b][d] = v;
    }
    __syncthreads();
    const int c = cq*64 + (tid & 63);
    const int dg = tid >> 6;
    const float4* wrow = (const float4*)(Wuk + (size_t)c*(NH*HD) + h*HD + dg*32);
    float acc[NB] = {0,0,0,0};
    #pragma unroll
    for (int d4 = 0; d4 < 8; ++d4) {
      float4 w4 = wrow[d4];
      #pragma unroll
      for (int b = 0; b < NB; ++b)
        acc[b] += dot4(w4, *(const float4*)&qc_s[b][dg*32 + d4*4]);
    }
    #pragma unroll
    for (int b = 0; b < NB; ++b) part_s[b][tid] = acc[b];
    __syncthreads();
    if (tid < 64) {
      #pragma unroll
      for (int b = 0; b < NB; ++b) {
        float v = (part_s[b][tid] + part_s[b][tid+64] + part_s[b][tid+128] + part_s[b][tid+192]) * SCALE_F;
        ws[WS_QABS + (size_t)(b*NH + h)*CKV + cq*64 + tid] = v;
        qbf[(size_t)(b*NH + h)*KD + cq*64 + tid] = f2bf(v);
      }
    }
  } else {
    const int b = bid - 256;
    const double LN1E4 = 9.210340371976184;
    for (int pid = tid; pid < NH*32; pid += 256) {
      int h = pid >> 5, i = pid & 31;
      float x1 = 0.f, x2 = 0.f;
      #pragma unroll
      for (int p = 0; p < NP2; ++p) {
        const float* base = ws + WS_P2 + (size_t)(p*NB + b)*6144 + 4096 + h*RD + 2*i;
        x1 += base[0]; x2 += base[1];
      }
      double ang = 4096.0 * exp(-(double)i / 32.0 * LN1E4);
      float cs = (float)cos(ang), sn = (float)sin(ang);
      float o0 = (x1*cs - x2*sn) * SCALE_F;
      float o1 = (x1*sn + x2*cs) * SCALE_F;
      ws[WS_QROPE + (b*NH + h)*RD + 2*i]     = o0;
      ws[WS_QROPE + (b*NH + h)*RD + 2*i + 1] = o1;
      qbf[(size_t)(b*NH + h)*KD + 512 + 2*i]     = f2bf(o0);
      qbf[(size_t)(b*NH + h)*KD + 512 + 2*i + 1] = f2bf(o1);
    }
  }
}

// ---------------- L4: scores via MFMA bf16 — q from global (no q LDS) --------
// block: 32 heads × 32 keys × K=576; LDS 36.5 KB -> 4 blocks/CU. grid (129,4).
__global__ __launch_bounds__(256)
void k_scores_mfma(float* __restrict__ ws) {
  __shared__ unsigned short kv_s[32 * QKB_STR];
  const unsigned short* kvbf = (const unsigned short*)(ws + WS_KVBF);
  const unsigned short* qbf  = (const unsigned short*)(ws + WS_QBF);
  const int tid = threadIdx.x;
  const int b  = blockIdx.y;
  const int k0 = blockIdx.x * 32;
  {
    const int r = tid >> 3, u0 = tid & 7;
    const int k = k0 + r;
    const unsigned short* ksrc = (k <= SS) ? (kvbf + ((size_t)b*SK + k)*KD) : nullptr;
    #pragma unroll
    for (int j = 0; j < 9; ++j) {
      int u = (u0 + 8*j) * 8;
      uint4 kvv = {0u, 0u, 0u, 0u};
      if (ksrc) kvv = *(const uint4*)(ksrc + u);
      *(uint4*)&kv_s[r*QKB_STR + u] = kvv;
    }
  }
  __syncthreads();
  const int wid = tid >> 6, lane = tid & 63;
  const int m0 = (wid & 1) * 16;
  const int n0 = (wid >> 1) * 16;
  const int l15 = lane & 15, lq = lane >> 4;
  const unsigned short* arow = qbf + (size_t)(b*NH + m0 + l15)*KD + lq*8;
  const unsigned short* brow = &kv_s[(n0 + l15)*QKB_STR + lq*8];
  f32x4 acc = {0.f, 0.f, 0.f, 0.f};
  #pragma unroll
  for (int ks = 0; ks < 18; ++ks) {
    short8v a = *(const short8v*)(arow + ks*32);
    short8v bb = *(const short8v*)(brow + ks*32);
    acc = __builtin_amdgcn_mfma_f32_16x16x32_bf16(a, bb, acc, 0, 0, 0);
  }
  const int key = k0 + n0 + l15;
  if (key <= SS) {
    #pragma unroll
    for (int r = 0; r < 4; ++r) {
      int h = m0 + lq*4 + r;
      ws[WS_SCA + (size_t)(b*NH + h)*SKP + key] = acc[r];
    }
  }
}

// ---------------- L5: softmax(SCA + mask) -> bf16 probs in PBF ---------------
__global__ __launch_bounds__(256)
void k_softmax(const float* __restrict__ mask, float* __restrict__ ws) {
  __shared__ float red[256];
  unsigned short* pbf = (unsigned short*)(ws + WS_PBF);
  const int tid = threadIdx.x;
  const int b = blockIdx.x >> 5;
  const float* sa = ws + WS_SCA + (size_t)blockIdx.x * SKP;
  unsigned short* prow = pbf + (size_t)blockIdx.x * PBF_STR;
  const float* mrow = mask + (size_t)b * SK;
  float v[17];
  float m = -INFINITY;
  #pragma unroll
  for (int r = 0; r < 17; ++r) {
    int k = tid + r*256;
    v[r] = (k < SK) ? (sa[k] + mrow[k] * (-1e9f)) : -INFINITY;
    m = fmaxf(m, v[r]);
  }
  red[tid] = m; __syncthreads();
  for (int st = 128; st > 0; st >>= 1) {
    if (tid < st) red[tid] = fmaxf(red[tid], red[tid+st]);
    __syncthreads();
  }
  m = red[0]; __syncthreads();
  float e[17];
  float l = 0.f;
  #pragma unroll
  for (int r = 0; r < 17; ++r) {
    int k = tid + r*256;
    e[r] = (k < SK) ? __expf(v[r] - m) : 0.f;
    l += e[r];
  }
  red[tid] = l; __syncthreads();
  for (int st = 128; st > 0; st >>= 1) {
    if (tid < st) red[tid] += red[tid+st];
    __syncthreads();
  }
  float inv = 1.f / red[0];
  #pragma unroll
  for (int r = 0; r < 17; ++r) {
    int k = tid + r*256;
    if (k < SK) prow[k] = f2bf(e[r] * inv);
  }
}

// ---------------- L6: pv via MFMA — in-LDS kv transpose ----------------------
// block: 32 heads × 128 keys × 128-c quarter; grid (NPV=32, 4, 4) = 512.
// 4 sub-chunks of 32 keys: stage kvT[128 c][32 k] (transposed), then
// wave = (m-tile w&1, n-octant w>>1): 4 n-tiles × 1 MFMA each.
// A = probs from global PBF (rows contiguous in k). Tail key SS in k_uv2.
__global__ __launch_bounds__(256)
void k_pv_mfma(float* __restrict__ ws) {
  __shared__ unsigned short kvT_s[128 * TV_STR];
  const unsigned short* kvbf = (const unsigned short*)(ws + WS_KVBF);
  const unsigned short* pbf  = (const unsigned short*)(ws + WS_PBF);
  const int tid = threadIdx.x;
  const int b  = blockIdx.z;
  const int c0 = blockIdx.y * 128;
  const int k0 = blockIdx.x * 128;
  const int wid = tid >> 6, lane = tid & 63;
  const int l15 = lane & 15, lq = lane >> 4;
  const int m0 = (wid & 1) * 16;          // head tile base
  const int nq = (wid >> 1) * 4;          // n-tile octant base (4 tiles)
  f32x4 acc[4] = {{0,0,0,0},{0,0,0,0},{0,0,0,0},{0,0,0,0}};
  const int kk_st = tid & 31, cgrp = tid >> 5;   // staging mapping
  #pragma unroll
  for (int sc = 0; sc < 4; ++sc) {
    const int ks0 = k0 + sc*32;
    // stage kvT: [128 c][32 k] from kvbf rows (lanes = keys -> conflict-free writes)
    {
      const unsigned short* src = kvbf + ((size_t)b*SK + ks0 + kk_st)*KD + c0 + cgrp*16;
      #pragma unroll
      for (int half = 0; half < 2; ++half) {
        ushort4 v0 = *(const ushort4*)(src + half*8);
        ushort4 v1 = *(const ushort4*)(src + half*8 + 4);
        int cb = cgrp*16 + half*8;
        kvT_s[(cb+0)*TV_STR + kk_st] = v0.x;
        kvT_s[(cb+1)*TV_STR + kk_st] = v0.y;
        kvT_s[(cb+2)*TV_STR + kk_st] = v0.z;
        kvT_s[(cb+3)*TV_STR + kk_st] = v0.w;
        kvT_s[(cb+4)*TV_STR + kk_st] = v1.x;
        kvT_s[(cb+5)*TV_STR + kk_st] = v1.y;
        kvT_s[(cb+6)*TV_STR + kk_st] = v1.z;
        kvT_s[(cb+7)*TV_STR + kk_st] = v1.w;
      }
    }
    __syncthreads();
    // A fragment: P[h = m0+l15][k = ks0 + lq*8 + i] from global
    short8v a = *(const short8v*)(pbf + (size_t)(b*NH + m0 + l15)*PBF_STR + ks0 + lq*8);
    #pragma unroll
    for (int nt = 0; nt < 4; ++nt) {
      const unsigned short* brow = &kvT_s[((nq + nt)*16 + l15)*TV_STR + lq*8];
      short8v bb = *(const short8v*)(brow);
      acc[nt] = __builtin_amdgcn_mfma_f32_16x16x32_bf16(a, bb, acc[nt], 0, 0, 0);
    }
    __syncthreads();
  }
  // epilogue: D col = c (l15), row = head (lq*4 + r)
  #pragma unroll
  for (int nt = 0; nt < 4; ++nt) {
    const int c = c0 + (nq + nt)*16 + l15;
    #pragma unroll
    for (int r = 0; r < 4; ++r) {
      int h = m0 + lq*4 + r;
      ws[WS_OPART + (((size_t)blockIdx.x*NB + b)*NH + h)*CKV + c] = acc[nt][r];
    }
  }
}

// ------- L7: uv with OPART self-reduce pre-phase + tail-key (SS) term --------
__global__ __launch_bounds__(256)
void k_uv2(const float* __restrict__ Wuv, float* __restrict__ ws) {
  __shared__ float4 red_s[4][NB][64];
  __shared__ float ol_s[NB][2][32];
  const unsigned short* kvbf = (const unsigned short*)(ws + WS_KVBF);
  const unsigned short* pbf  = (const unsigned short*)(ws + WS_PBF);
  const int tid = threadIdx.x;
  const int x = blockIdx.x & 15, y = blockIdx.x >> 4;
  {
    const int b = tid >> 6, hh = (tid >> 5) & 1, ci = tid & 31;
    const int h = 2*x + hh, c = y*32 + ci;
    const float* base = ws + WS_OPART + ((size_t)b*NH + h)*CKV + c;
    float s = 0.f;
    #pragma unroll 8
    for (int p = 0; p < NPV; ++p) s += base[(size_t)p*(NB*NH*CKV)];
    // tail key SS (not covered by pv chunks)
    s += bf2f(pbf[(size_t)(b*NH + h)*PBF_STR + SS]) *
         bf2f(kvbf[((size_t)b*SK + SS)*KD + c]);
    ol_s[b][hh][ci] = s;
  }
  __syncthreads();
  const int lane = tid & 63, csub = tid >> 6;
  const int col4 = x * 64 + lane;
  const int hh = (col4 >> 5) & 1;
  const float4* wp = (const float4*)Wuv + (size_t)(y*32 + csub*8) * 1024 + col4;
  float4 acc[NB] = {};
  #pragma unroll
  for (int i = 0; i < 8; ++i) {
    float4 w4 = wp[(size_t)i * 1024];
    #pragma unroll
    for (int b = 0; b < NB; ++b)
      fma4(acc[b], ol_s[b][hh][csub*8 + i], w4);
  }
  #pragma unroll
  for (int b = 0; b < NB; ++b) red_s[csub][b][lane] = acc[b];
  __syncthreads();
  if (csub == 0) {
    #pragma unroll
    for (int b = 0; b < NB; ++b) {
      float4 s = red_s[0][b][lane];
      #pragma unroll
      for (int j = 1; j < 4; ++j) {
        float4 v = red_s[j][b][lane];
        s.x += v.x; s.y += v.y; s.z += v.z; s.w += v.w;
      }
      *(float4*)(ws + WS_UVPART + (size_t)(y*NB + b)*HID + col4*4) = s;
    }
  }
}

// ------- L8: wo with UVPART self-reduce pre-phase ----------------------------
__global__ __launch_bounds__(256)
void k_wo2(const float* __restrict__ Wo, float* __restrict__ ws) {
  __shared__ float4 red_s[4][NB][64];
  __shared__ float at_s[NB][128];
  const int tid = threadIdx.x;
  const int x = blockIdx.x & 15, y = blockIdx.x >> 4;
  {
    const int b = tid >> 6, q = tid & 63;
    #pragma unroll
    for (int e = 0; e < 2; ++e) {
      int idx = q*2 + e;
      const float* base = ws + WS_UVPART + (size_t)b*HID + y*128 + idx;
      float s = 0.f;
      #pragma unroll
      for (int p = 0; p < NUV; ++p) s += base[(size_t)p*(NB*HID)];
      at_s[b][idx] = s;
    }
  }
  __syncthreads();
  const int lane = tid & 63, ksub = tid >> 6;
  const int col4 = x * 64 + lane;
  const float4* wp = (const float4*)Wo + (size_t)(y*128 + ksub*32) * 1024 + col4;
  float4 acc[NB] = {};
  #pragma unroll 8
  for (int i = 0; i < 32; ++i) {
    float4 w4 = wp[(size_t)i * 1024];
    #pragma unroll
    for (int b = 0; b < NB; ++b)
      fma4(acc[b], at_s[b][ksub*32 + i], w4);
  }
  #pragma unroll
  for (int b = 0; b < NB; ++b) red_s[ksub][b][lane] = acc[b];
  __syncthreads();
  if (ksub == 0) {
    #pragma unroll
    for (int b = 0; b < NB; ++b) {
      float4 s = red_s[0][b][lane];
      #pragma unroll
      for (int j = 1; j < 4; ++j) {
        float4 v = red_s[j][b][lane];
        s.x += v.x; s.y += v.y; s.z += v.z; s.w += v.w;
      }
      *(float4*)(ws + WS_WOPART + (size_t)(y*NB + b)*HID + col4*4) = s;
    }
  }
}

// ---------------- L9: out = sum_p WOPART[p] ----------------------------------
__global__ __launch_bounds__(256)
void k_reduce5(const float* __restrict__ ws, float* __restrict__ out) {
  const int idx = blockIdx.x * 256 + threadIdx.x;
  float4 s = {};
  #pragma unroll 8
  for (int p = 0; p < NWO; ++p) {
    float4 v = *(const float4*)(ws + WS_WOPART + (size_t)p*(NB*HID) + (size_t)idx*4);
    s.x += v.x; s.y += v.y; s.z += v.z; s.w += v.w;
  }
  *(float4*)(out + (size_t)idx*4) = s;
}

extern "C" void kernel_launch(void* const* d_in, const int* in_sizes, int n_in,
                              void* d_out, int out_size, void* d_ws, size_t ws_size,
                              hipStream_t stream) {
  (void)in_sizes; (void)n_in; (void)out_size; (void)ws_size;
  const float* hidden = (const float*)d_in[0];
  const float* mask   = (const float*)d_in[1];
  const float* ckv_c  = (const float*)d_in[2];
  const float* kr_c   = (const float*)d_in[3];
  const float* Wdkv   = (const float*)d_in[4];
  const float* Wuk    = (const float*)d_in[5];
  const float* Wuv    = (const float*)d_in[6];
  const float* Wdq    = (const float*)d_in[7];
  const float* Wuq    = (const float*)d_in[8];
  const float* Wqr    = (const float*)d_in[9];
  const float* Wkr    = (const float*)d_in[10];
  const float* Wo     = (const float*)d_in[11];
  float* out = (float*)d_out;
  float* ws  = (float*)d_ws;
  float* out_ckv = out + NB*HID;
  float* out_kr  = out + NB*HID + (size_t)NB*SK*CKV;

  k_proj1copy<<<9792, 256, 0, stream>>>(hidden, Wdkv, Wdq, Wkr, ws,
                                        (const float4*)ckv_c, (const float4*)kr_c,
                                        (float4*)out_ckv, (float4*)out_kr);
  k_proj2r1<<<585, 256, 0, stream>>>(Wuq, Wqr, ws, out_ckv, out_kr);
  k_absorb_rope<<<260, 256, 0, stream>>>(Wuk, ws);
  k_scores_mfma<<<dim3(129, 4), 256, 0, stream>>>(ws);
  k_softmax<<<NB*NH, 256, 0, stream>>>(mask, ws);
  k_pv_mfma<<<dim3(NPV, 4, 4), 256, 0, stream>>>(ws);
  k_uv2<<<256, 256, 0, stream>>>(Wuv, ws);
  k_wo2<<<512, 256, 0, stream>>>(Wo, ws);
  k_reduce5<<<16, 256, 0, stream>>>(ws, out);
}